// Round 9
// baseline (334.754 us; speedup 1.0000x reference)
//
#include <hip/hip_runtime.h>

// Problem constants (from reference setup_inputs)
#define BB 4
#define CC 64
#define HH 56
#define WW 56
#define HW (HH*WW)

typedef unsigned short u16;
typedef __attribute__((ext_vector_type(8))) short bf16x8;
typedef __attribute__((ext_vector_type(4))) float f32x4;

__device__ __forceinline__ u16 f2bf(float f) {
    union { float f; unsigned u; } c; c.f = f;
    unsigned u = c.u;
    u = (u + 0x7FFFu + ((u >> 16) & 1u)) >> 16;   // RNE
    return (u16)u;
}
__device__ __forceinline__ float bf2f(u16 v) {
    union { unsigned u; float f; } c; c.u = ((unsigned)v) << 16;
    return c.f;
}

// ---------------------------------------------------------------------------
// Fused prep: all weight reshape/cast + 128B zero page in ONE launch.
// ---------------------------------------------------------------------------
#define R1 102400
#define R2 351232
#define R3 4096
#define R4 1600
#define R5 3136
#define R6 64
__global__ __launch_bounds__(256)
void prep_all_kernel(const float* __restrict__ ow1, const float* __restrict__ ow2,
                     const float* __restrict__ pw,  const float* __restrict__ dw1,
                     const float* __restrict__ dw2,
                     u16* __restrict__ w2t1, u16* __restrict__ w2t2,
                     u16* __restrict__ pwT, float* __restrict__ dwT1,
                     float* __restrict__ dwT2, u16* __restrict__ zb) {
    const int i = blockIdx.x*256 + threadIdx.x;
    if (i < R1) {
        const int ic = i & 63, n = (i >> 6) & 63, tap = i >> 12;
        w2t1[i] = f2bf((n < 50) ? ow1[((size_t)n*64 + ic)*25 + tap] : 0.f);
    } else if (i < R1+R2) {
        const int j = i - R1;
        const int ic = j & 63, n = (j >> 6) % 112, tap = j / 7168;
        w2t2[j] = f2bf((n < 98) ? ow2[((size_t)n*64 + ic)*49 + tap] : 0.f);
    } else if (i < R1+R2+R3) {
        const int j = i - (R1+R2);
        pwT[j] = f2bf(pw[j]);
    } else if (i < R1+R2+R3+R4) {
        const int j = i - (R1+R2+R3);
        const int c = j & 63, k = j >> 6;
        dwT1[j] = dw1[c*25 + k];
    } else if (i < R1+R2+R3+R4+R5) {
        const int j = i - (R1+R2+R3+R4);
        const int c = j & 63, k = j >> 6;
        dwT2[j] = dw2[c*49 + k];
    } else if (i < R1+R2+R3+R4+R5+R6) {
        zb[i - (R1+R2+R3+R4+R5)] = 0;
    }
}

// ---------------------------------------------------------------------------
// Transpose + cast: in (B,CC,HW) fp32 -> out (B,HW,CC) bf16.
// ---------------------------------------------------------------------------
__global__ __launch_bounds__(256)
void transpose_bf16_kernel(const float* __restrict__ in, u16* __restrict__ out) {
    __shared__ u16 tile[64][72];
    const int blk = blockIdx.x;
    const int b   = blk / (HW/64);
    const int p0  = (blk % (HW/64))*64;
    const int t   = threadIdx.x;

    const int px  = t & 63, icq = t >> 6;
    const float* ip = in + ((size_t)b*CC + icq*16)*HW + p0 + px;
    #pragma unroll
    for (int i = 0; i < 16; ++i)
        tile[px][icq*16 + i] = f2bf(ip[(size_t)i*HW]);
    __syncthreads();

    const int px2 = t >> 2, g = t & 3;
    u16* op = out + ((size_t)b*HW + p0 + px2)*64 + g*16;
    const uint4* s = (const uint4*)&tile[px2][g*16];
    ((uint4*)op)[0] = s[0];
    ((uint4*)op)[1] = s[1];
}

// ---------------------------------------------------------------------------
// Barrier-free MFMA implicit-GEMM conv, deep-pipelined: wave = 16 px x one
// 16-wide n-tile (blockIdx.y). Tap loop FULLY unrolled (compile-time shifts
// -> all 4*KK load addresses are base+const, hoistable); invalid taps load
// from a 128B zero page (pointer cndmask, not 16 data cndmasks).
// __launch_bounds__(256,4) caps VGPR at ~128 so residency is kept while the
// scheduler keeps ~6 taps (24 loads) in flight per wave.
// A: lane = A[m=lane&15][k=quad*8+j]; B: lane = B[k=quad*8+j][n=lane&15];
// C: n=lane&15, m=quad*4+reg.
// ---------------------------------------------------------------------------
template<int K, int DIL, int PAD, int COUT, int NP>
__global__ __launch_bounds__(256, 4)
void conv_mfma_kernel(const u16* __restrict__ xT, const u16* __restrict__ w2t,
                      const float* __restrict__ bias, const u16* __restrict__ zb,
                      float* __restrict__ out) {
    constexpr int KK = K*K;
    const int nm   = HW/64;
    const int b    = blockIdx.x / nm;
    const int p0   = (blockIdx.x % nm)*64 + (threadIdx.x >> 6)*16;
    const int nt0  = blockIdx.y;
    const int lane = threadIdx.x & 63;
    const int r    = lane & 15;
    const int quad = lane >> 4;
    const int p    = p0 + r;
    const int py   = p / WW;
    const int pxx  = p % WW;
    const u16* abase = xT + (size_t)b*HW*64 + (size_t)quad*8;
    const u16* bbase = w2t + ((size_t)nt0*16 + r)*64 + quad*8;
    const u16* zp    = zb + quad*8;

    f32x4 acc = (f32x4){0.f,0.f,0.f,0.f};

    #pragma unroll
    for (int tap = 0; tap < KK; ++tap) {
        const int dyy = (tap/K)*DIL - PAD;      // compile-time constants
        const int dxx = (tap%K)*DIL - PAD;
        const int yy  = py + dyy, xx2 = pxx + dxx;
        const bool valid = ((unsigned)yy < (unsigned)HH) && ((unsigned)xx2 < (unsigned)WW);
        const u16* ap = valid ? (abase + (size_t)(p + (dyy*WW + dxx))*64) : zp;

        const bf16x8 av0 = *(const bf16x8*)(ap);
        const bf16x8 av1 = *(const bf16x8*)(ap + 32);
        const u16* bp = bbase + (size_t)tap*NP*64;
        const bf16x8 bv0 = *(const bf16x8*)(bp);
        const bf16x8 bv1 = *(const bf16x8*)(bp + 32);
        acc = __builtin_amdgcn_mfma_f32_16x16x32_bf16(av0, bv0, acc, 0, 0, 0);
        acc = __builtin_amdgcn_mfma_f32_16x16x32_bf16(av1, bv1, acc, 0, 0, 0);
    }

    const int n = nt0*16 + r;
    if (n < COUT) {
        const float bv = bias[n];
        float* op = out + ((size_t)b*COUT + n)*HW + p0 + quad*4;
        #pragma unroll
        for (int r2 = 0; r2 < 4; ++r2) op[r2] = acc[r2] + bv;
    }
}

// ---------------------------------------------------------------------------
// Channel-last deformable bilinear + depthwise. Wave = one pixel, lane =
// channel; offset loads wave-uniform (scalarized via readfirstlane base).
// ---------------------------------------------------------------------------
template<int K, int DIL, int PAD>
__global__ __launch_bounds__(256)
void deform_cl_kernel(const u16* __restrict__ inT, const float* __restrict__ off,
                      const float* __restrict__ dwT, u16* __restrict__ outT) {
    constexpr int KK = K*K;
    const int gw   = __builtin_amdgcn_readfirstlane((blockIdx.x*256 + threadIdx.x) >> 6);
    const int lane = threadIdx.x & 63;
    const int p = gw % HW;
    const int b = gw / HW;
    const int h = p / WW, w = p % WW;

    const u16*   ib   = inT + (size_t)b*HW*64 + lane;
    const float* offp = off + (size_t)b*(2*KK)*HW + p;

    float acc = 0.f;
    #pragma unroll 7
    for (int k = 0; k < KK; ++k) {
        const float dy = offp[(size_t)(2*k  )*HW];
        const float dx = offp[(size_t)(2*k+1)*HW];
        const float py = (float)(h + (k/K)*DIL - PAD) + dy;
        const float px = (float)(w + (k%K)*DIL - PAD) + dx;
        const float y0f = floorf(py), x0f = floorf(px);
        const float wy1 = py - y0f,  wx1 = px - x0f;
        const float wy0 = 1.f - wy1, wx0 = 1.f - wx1;
        const int y0 = (int)y0f, x0 = (int)x0f;

        const int y0c = min(max(y0,   0), HH-1);
        const int y1c = min(max(y0+1, 0), HH-1);
        const int x0c = min(max(x0,   0), WW-1);
        const int x1c = min(max(x0+1, 0), WW-1);
        const float gy0 = wy0 * ((y0   >= 0 && y0   < HH) ? 1.f : 0.f);
        const float gy1 = wy1 * ((y0+1 >= 0 && y0+1 < HH) ? 1.f : 0.f);
        const float gx0 = wx0 * ((x0   >= 0 && x0   < WW) ? 1.f : 0.f);
        const float gx1 = wx1 * ((x0+1 >= 0 && x0+1 < WW) ? 1.f : 0.f);

        const int r0 = y0c*WW, r1 = y1c*WW;
        const float v00 = bf2f(ib[(size_t)(r0 + x0c)*64]);
        const float v01 = bf2f(ib[(size_t)(r0 + x1c)*64]);
        const float v10 = bf2f(ib[(size_t)(r1 + x0c)*64]);
        const float v11 = bf2f(ib[(size_t)(r1 + x1c)*64]);

        const float s = (v00*gx0 + v01*gx1)*gy0 + (v10*gx0 + v11*gx1)*gy1;
        acc += s * dwT[k*CC + lane];
    }
    outT[(size_t)gw*64 + lane] = f2bf(acc);
}

// ---------------------------------------------------------------------------
// Pointwise 1x1 via MFMA + fused residual multiply; wave = 16 px x 1 n-tile.
// ---------------------------------------------------------------------------
__global__ __launch_bounds__(256)
void pw_mfma_kernel(const u16* __restrict__ a2T, const u16* __restrict__ pwT,
                    const float* __restrict__ pb, const float* __restrict__ x,
                    float* __restrict__ out) {
    const int nm = HW/64;
    const int b  = blockIdx.x / nm;
    const int p0 = (blockIdx.x % nm)*64 + (threadIdx.x >> 6)*16;
    const int nt = blockIdx.y;
    const int lane = threadIdx.x & 63;
    const int r = lane & 15, quad = lane >> 4;

    const u16* ap = a2T + ((size_t)b*HW + p0 + r)*64 + quad*8;
    f32x4 acc = (f32x4){0.f,0.f,0.f,0.f};
    #pragma unroll
    for (int ks = 0; ks < 2; ++ks) {
        const bf16x8 av = *(const bf16x8*)(ap + ks*32);
        const bf16x8 bv = *(const bf16x8*)(pwT + ((size_t)(nt*16 + r))*64 + ks*32 + quad*8);
        acc = __builtin_amdgcn_mfma_f32_16x16x32_bf16(av, bv, acc, 0, 0, 0);
    }

    const int n = nt*16 + r;
    const float bv = pb[n];
    const size_t base = ((size_t)b*CC + n)*HW + p0 + quad*4;
    #pragma unroll
    for (int r2 = 0; r2 < 4; ++r2)
        out[base + r2] = x[base + r2] * (acc[r2] + bv);
}

// ======================= fallback fp32 kernels (low ws) =====================
template<int K, int DIL, int PAD, int COUT, int OCB>
__global__ __launch_bounds__(256)
void off_conv_sg_kernel(const float* __restrict__ in, const float* __restrict__ wgt,
                        const float* __restrict__ bias, float* __restrict__ out) {
    constexpr int KK = K*K;
    const int nOB = COUT / OCB;
    const int b   = blockIdx.x / nOB;
    const int oc0 = (blockIdx.x % nOB) * OCB;
    const int x   = threadIdx.x;
    const int h   = blockIdx.y*4 + threadIdx.y;

    float acc[OCB];
    #pragma unroll
    for (int o = 0; o < OCB; ++o) acc[o] = bias[oc0+o];

    const float* inb = in + (size_t)b*CC*HW;
    const float* wb  = wgt + (size_t)oc0*CC*KK;

    for (int ic = 0; ic < CC; ++ic) {
        const float* inp = inb + ic*HW;
        const float* wp  = wb + ic*KK;
        #pragma unroll
        for (int ky = 0; ky < K; ++ky) {
            const int  y  = h + ky*DIL - PAD;
            const bool yv = (y >= 0) && (y < HH);
            const int  yc = yv ? y : 0;
            const float* row = inp + yc*WW;
            #pragma unroll
            for (int kx = 0; kx < K; ++kx) {
                const int  xx = x + kx*DIL - PAD;
                const bool v  = yv && (xx >= 0) && (xx < WW);
                const int  xc = (xx < 0) ? 0 : ((xx >= WW) ? (WW-1) : xx);
                float val = row[xc];
                val = v ? val : 0.f;
                const int t = ky*K + kx;
                #pragma unroll
                for (int o = 0; o < OCB; ++o)
                    acc[o] += wp[(size_t)o*CC*KK + t] * val;
            }
        }
    }

    if (x >= WW) return;
    #pragma unroll
    for (int o = 0; o < OCB; ++o)
        out[((size_t)b*COUT + oc0 + o)*HW + h*WW + x] = acc[o];
}

template<int K, int DIL, int PAD>
__global__ __launch_bounds__(64)
void deform_dw_full_kernel(const float* __restrict__ in, const float* __restrict__ off,
                           const float* __restrict__ dw, float* __restrict__ out) {
    constexpr int KK = K*K;
    const int idx = blockIdx.x*64 + threadIdx.x;
    const int x = idx % WW;
    const int h = (idx / WW) % HH;
    const int c = (idx / HW) % CC;
    const int b = idx / (CC*HW);

    const float* inp  = in  + ((size_t)b*CC + c)*HW;
    const float* offp = off + (size_t)b*(2*KK)*HW + h*WW + x;
    const float* dwp  = dw  + c*KK;

    float acc = 0.f;
    #pragma unroll 7
    for (int k = 0; k < KK; ++k) {
        const float dy = offp[(2*k  )*HW];
        const float dx = offp[(2*k+1)*HW];
        const float py = (float)(h + (k/K)*DIL - PAD) + dy;
        const float px = (float)(x + (k%K)*DIL - PAD) + dx;
        const float y0f = floorf(py), x0f = floorf(px);
        const float wy1 = py - y0f,  wx1 = px - x0f;
        const float wy0 = 1.f - wy1, wx0 = 1.f - wx1;
        const int y0 = (int)y0f, x0 = (int)x0f;

        const int y0c = min(max(y0,   0), HH-1);
        const int y1c = min(max(y0+1, 0), HH-1);
        const int x0c = min(max(x0,   0), WW-1);
        const int x1c = min(max(x0+1, 0), WW-1);
        const float my0 = (y0   >= 0 && y0   < HH) ? 1.f : 0.f;
        const float my1 = (y0+1 >= 0 && y0+1 < HH) ? 1.f : 0.f;
        const float mx0 = (x0   >= 0 && x0   < WW) ? 1.f : 0.f;
        const float mx1 = (x0+1 >= 0 && x0+1 < WW) ? 1.f : 0.f;

        const float v00 = inp[y0c*WW + x0c];
        const float v01 = inp[y0c*WW + x1c];
        const float v10 = inp[y1c*WW + x0c];
        const float v11 = inp[y1c*WW + x1c];

        const float gx0 = wx0*mx0, gx1 = wx1*mx1;
        const float s = (v00*gx0 + v01*gx1) * (wy0*my0)
                      + (v10*gx0 + v11*gx1) * (wy1*my1);
        acc += s * dwp[k];
    }
    out[idx] = acc;
}

__global__ __launch_bounds__(256)
void pw_mul_kernel(const float* __restrict__ x, const float* __restrict__ a2,
                   const float* __restrict__ pw, const float* __restrict__ pb,
                   float* __restrict__ out) {
    constexpr int HW4 = HW/4;
    const int t = blockIdx.x*256 + threadIdx.x;
    if (t >= BB*CC*HW4) return;
    const int sp4 = t % HW4;
    const int oc  = (t / HW4) % CC;
    const int b   = t / (CC*HW4);

    const float4* ap = (const float4*)(a2 + (size_t)b*CC*HW) + sp4;
    const float4* wp4 = (const float4*)(pw + oc*CC);
    const float pbv = pb[oc];
    float4 acc = make_float4(pbv, pbv, pbv, pbv);
    #pragma unroll 4
    for (int ic4 = 0; ic4 < CC/4; ++ic4) {
        const float4 w = wp4[ic4];
        float4 a0 = ap[(ic4*4+0)*HW4];
        float4 a1 = ap[(ic4*4+1)*HW4];
        float4 a2v = ap[(ic4*4+2)*HW4];
        float4 a3 = ap[(ic4*4+3)*HW4];
        acc.x += w.x*a0.x + w.y*a1.x + w.z*a2v.x + w.w*a3.x;
        acc.y += w.x*a0.y + w.y*a1.y + w.z*a2v.y + w.w*a3.y;
        acc.z += w.x*a0.z + w.y*a1.z + w.z*a2v.z + w.w*a3.z;
        acc.w += w.x*a0.w + w.y*a1.w + w.z*a2v.w + w.w*a3.w;
    }
    const float4 xv = ((const float4*)x)[t];
    float4 r;
    r.x = xv.x*acc.x; r.y = xv.y*acc.y; r.z = xv.z*acc.z; r.w = xv.w*acc.w;
    ((float4*)out)[t] = r;
}

extern "C" void kernel_launch(void* const* d_in, const int* in_sizes, int n_in,
                              void* d_out, int out_size, void* d_ws, size_t ws_size,
                              hipStream_t stream) {
    const float* x      = (const float*)d_in[0];
    const float* off_w1 = (const float*)d_in[1];
    const float* off_b1 = (const float*)d_in[2];
    const float* dw_w1  = (const float*)d_in[3];
    const float* off_w2 = (const float*)d_in[4];
    const float* off_b2 = (const float*)d_in[5];
    const float* dw_w2  = (const float*)d_in[6];
    const float* pw_w   = (const float*)d_in[7];
    const float* pw_b   = (const float*)d_in[8];
    float* out = (float*)d_out;

    const size_t nF    = (size_t)BB*CC*HW;
    const size_t attnB = nF*sizeof(float);                 // 3,211,264
    const size_t off2B = (size_t)BB*98*HW*sizeof(float);   // 4,917,248
    const size_t chB   = (size_t)BB*HW*64*sizeof(u16);     // 1,605,632
    char* ws = (char*)d_ws;

    const int n    = (int)nF;
    const int dbl  = n/64;
    const int pbl  = (n/4 + 255)/256;
    dim3 cblk(64,4);
    dim3 rgrd1(BB*(50/5), HH/4);
    dim3 rgrd2(BB*(98/7), HH/4);
    const int tgrid = BB*(HW/64);            // 196
    dim3 cgrd1(tgrid, 4);                    // conv1: NP=64  -> 4 n-tiles
    dim3 cgrd2(tgrid, 7);                    // conv2: NP=112 -> 7 n-tiles
    dim3 pgrd(tgrid, 4);                     // pw:    64 ch  -> 4 n-tiles
    const int dgrid = BB*HW/4;               // wave-per-pixel deform

    const size_t oOFF  = 0;
    const size_t oXT   = oOFF + off2B;
    const size_t oA1T  = oXT  + chB;
    const size_t oA2T  = oA1T + chB;
    const size_t oW1   = oA2T + chB;
    const size_t oW2   = oW1  + (size_t)R1*2;
    const size_t oPWT  = oW2  + (size_t)R2*2;
    const size_t oDW1  = oPWT + (size_t)R3*2;
    const size_t oDW2  = oDW1 + (size_t)R4*4;
    const size_t oZB   = oDW2 + (size_t)R5*4;
    const size_t TOT   = oZB  + (size_t)R6*2;

    if (ws_size >= TOT) {
        float* off_buf = (float*)(ws + oOFF);
        u16*   xT      = (u16*)(ws + oXT);
        u16*   a1T     = (u16*)(ws + oA1T);
        u16*   a2T     = (u16*)(ws + oA2T);
        u16*   w2t1    = (u16*)(ws + oW1);
        u16*   w2t2    = (u16*)(ws + oW2);
        u16*   pwT     = (u16*)(ws + oPWT);
        float* dwT1    = (float*)(ws + oDW1);
        float* dwT2    = (float*)(ws + oDW2);
        u16*   zb      = (u16*)(ws + oZB);

        prep_all_kernel<<<(R1+R2+R3+R4+R5+R6+255)/256, 256, 0, stream>>>(
            off_w1, off_w2, pw_w, dw_w1, dw_w2, w2t1, w2t2, pwT, dwT1, dwT2, zb);
        transpose_bf16_kernel<<<tgrid, 256, 0, stream>>>(x, xT);

        conv_mfma_kernel<5,1,2,50,64><<<cgrd1, 256, 0, stream>>>(xT, w2t1, off_b1, zb, off_buf);
        deform_cl_kernel<5,1,2><<<dgrid, 256, 0, stream>>>(xT, off_buf, dwT1, a1T);

        conv_mfma_kernel<7,3,9,98,112><<<cgrd2, 256, 0, stream>>>(a1T, w2t2, off_b2, zb, off_buf);
        deform_cl_kernel<7,3,9><<<dgrid, 256, 0, stream>>>(a1T, off_buf, dwT2, a2T);

        pw_mfma_kernel<<<pgrd, 256, 0, stream>>>(a2T, pwT, pw_b, x, out);
    } else if (ws_size >= off2B + attnB) {
        float* off_buf = (float*)ws;
        float* attn1   = (float*)d_out;
        float* attn2   = (float*)(ws + off2B);
        off_conv_sg_kernel<5,1,2,50,5><<<rgrd1, cblk, 0, stream>>>(x, off_w1, off_b1, off_buf);
        deform_dw_full_kernel<5,1,2><<<dbl, 64, 0, stream>>>(x, off_buf, dw_w1, attn1);
        off_conv_sg_kernel<7,3,9,98,7><<<rgrd2, cblk, 0, stream>>>(attn1, off_w2, off_b2, off_buf);
        deform_dw_full_kernel<7,3,9><<<dbl, 64, 0, stream>>>(attn1, off_buf, dw_w2, attn2);
        pw_mul_kernel<<<pbl, 256, 0, stream>>>(x, attn2, pw_w, pw_b, out);
    } else {
        float* attn1 = (float*)d_out;
        float* attn2 = (float*)ws;
        float* off1  = (float*)ws;
        off_conv_sg_kernel<5,1,2,50,5><<<rgrd1, cblk, 0, stream>>>(x, off_w1, off_b1, off1);
        deform_dw_full_kernel<5,1,2><<<dbl, 64, 0, stream>>>(x, off1, dw_w1, attn1);
        float* off2 = (float*)(ws + attnB);
        off_conv_sg_kernel<7,3,9,98,7><<<rgrd2, cblk, 0, stream>>>(attn1, off_w2, off_b2, off2);
        deform_dw_full_kernel<7,3,9><<<dbl, 64, 0, stream>>>(attn1, off2, dw_w2, attn2);
        pw_mul_kernel<<<pbl, 256, 0, stream>>>(x, attn2, pw_w, pw_b, out);
    }
}

// Round 10
// 220.681 us; speedup vs baseline: 1.5169x; 1.5169x over previous
//
#include <hip/hip_runtime.h>

// Problem constants (from reference setup_inputs)
#define BB 4
#define CC 64
#define HH 56
#define WW 56
#define HW (HH*WW)

typedef unsigned short u16;
typedef __attribute__((ext_vector_type(8))) short bf16x8;
typedef __attribute__((ext_vector_type(4))) float f32x4;

__device__ __forceinline__ u16 f2bf(float f) {
    union { float f; unsigned u; } c; c.f = f;
    unsigned u = c.u;
    u = (u + 0x7FFFu + ((u >> 16) & 1u)) >> 16;   // RNE
    return (u16)u;
}
__device__ __forceinline__ float bf2f(u16 v) {
    union { unsigned u; float f; } c; c.u = ((unsigned)v) << 16;
    return c.f;
}

// ---------------------------------------------------------------------------
// Fused prep: all weight reshape/cast in ONE launch.
// ---------------------------------------------------------------------------
#define R1 102400
#define R2 351232
#define R3 4096
#define R4 1600
#define R5 3136
__global__ __launch_bounds__(256)
void prep_all_kernel(const float* __restrict__ ow1, const float* __restrict__ ow2,
                     const float* __restrict__ pw,  const float* __restrict__ dw1,
                     const float* __restrict__ dw2,
                     u16* __restrict__ w2t1, u16* __restrict__ w2t2,
                     u16* __restrict__ pwT, float* __restrict__ dwT1,
                     float* __restrict__ dwT2) {
    const int i = blockIdx.x*256 + threadIdx.x;
    if (i < R1) {
        const int ic = i & 63, n = (i >> 6) & 63, tap = i >> 12;
        w2t1[i] = f2bf((n < 50) ? ow1[((size_t)n*64 + ic)*25 + tap] : 0.f);
    } else if (i < R1+R2) {
        const int j = i - R1;
        const int ic = j & 63, n = (j >> 6) % 112, tap = j / 7168;
        w2t2[j] = f2bf((n < 98) ? ow2[((size_t)n*64 + ic)*49 + tap] : 0.f);
    } else if (i < R1+R2+R3) {
        const int j = i - (R1+R2);
        pwT[j] = f2bf(pw[j]);
    } else if (i < R1+R2+R3+R4) {
        const int j = i - (R1+R2+R3);
        const int c = j & 63, k = j >> 6;
        dwT1[j] = dw1[c*25 + k];
    } else if (i < R1+R2+R3+R4+R5) {
        const int j = i - (R1+R2+R3+R4);
        const int c = j & 63, k = j >> 6;
        dwT2[j] = dw2[c*49 + k];
    }
}

// ---------------------------------------------------------------------------
// Transpose + cast: in (B,CC,HW) fp32 -> out (B,HW,CC) bf16.
// ---------------------------------------------------------------------------
__global__ __launch_bounds__(256)
void transpose_bf16_kernel(const float* __restrict__ in, u16* __restrict__ out) {
    __shared__ u16 tile[64][72];
    const int blk = blockIdx.x;
    const int b   = blk / (HW/64);
    const int p0  = (blk % (HW/64))*64;
    const int t   = threadIdx.x;

    const int px  = t & 63, icq = t >> 6;
    const float* ip = in + ((size_t)b*CC + icq*16)*HW + p0 + px;
    #pragma unroll
    for (int i = 0; i < 16; ++i)
        tile[px][icq*16 + i] = f2bf(ip[(size_t)i*HW]);
    __syncthreads();

    const int px2 = t >> 2, g = t & 3;
    u16* op = out + ((size_t)b*HW + p0 + px2)*64 + g*16;
    const uint4* s = (const uint4*)&tile[px2][g*16];
    ((uint4*)op)[0] = s[0];
    ((uint4*)op)[1] = s[1];
}

__device__ __forceinline__ uint4 selz(bool v, uint4 a) {
    const uint4 z = make_uint4(0,0,0,0);
    return v ? a : z;
}

// ---------------------------------------------------------------------------
// LDS-staged MFMA implicit-GEMM conv. TA-throughput-optimized: the A-tile
// (64 px x 128 B) and B-tile (16 n x 128 B) are staged per tap with FULLY
// COALESCED uint4 loads (8 consecutive pixel-rows per wave-instr -> 8 line
// requests vs 16-line scatter of the direct-fragment version; 80 vs 256 line
// requests per block-tap). Fragments come from LDS via ds_read_b128 with an
// XOR chunk swizzle slot=(chunk+row)&7: stores AND reads both land 8 lanes
// per 4-bank group = wave64/b128 minimum -> conflict-free, no padding.
// Double-buffered, ONE __syncthreads per tap; next tap's global loads are
// prefetched into registers before the store+barrier.
// Block: 256 thr = 4 waves; tile 64 px x 16 n (nt0 = blockIdx.y).
// Fragment layouts (validated rounds 5-9):
//   A: lane = A[m=lane&15][k=quad*8+j]; B: lane = B[k=quad*8+j][n=lane&15];
//   C: n=lane&15, m=quad*4+reg.
// ---------------------------------------------------------------------------
template<int K, int DIL, int PAD, int COUT, int NP>
__global__ __launch_bounds__(256, 4)
void conv_mfma_lds_kernel(const u16* __restrict__ xT, const u16* __restrict__ w2t,
                          const float* __restrict__ bias, float* __restrict__ out) {
    constexpr int KK = K*K;
    __shared__ u16 Ab[2][64*64];
    __shared__ u16 Bb[2][16*64];

    const int nm   = HW/64;                       // 49
    const int b    = blockIdx.x / nm;
    const int p0   = (blockIdx.x % nm)*64;
    const int nt0  = blockIdx.y;
    const int t    = threadIdx.x;
    const int wave = t >> 6;
    const int lane = t & 63;

    // Staging mapping: thread stages 2 pixel-rows (spx, spx+32) x 16B chunk sc.
    const int spx = t >> 3;                       // 0..31
    const int sc  = t & 7;                        // chunk 0..7
    const int pA  = p0 + spx;
    const int pB  = p0 + spx + 32;
    const int pyA = pA / WW, pxA = pA % WW;
    const int pyB = pB / WW, pxB = pB % WW;
    const u16* xb = xT + (size_t)b*HW*64;
    const int sslotA = ((sc + spx) & 7)*8;        // same for spx+32 (32%8==0)
    const int bn  = t >> 3;                       // B row (threads t<128)
    const int bslot = ((sc + bn) & 7)*8;
    const u16* wbase = w2t + (size_t)nt0*16*64;

    // Compute mapping.
    const int r = lane & 15, quad = lane >> 4;
    const int mloc = wave*16 + r;
    const int arow = mloc*64, brow = r*64;
    const int a0s = ((quad     + mloc) & 7)*8;    // A slot, ks=0 (chunk=quad)
    const int a1s = ((quad + 4 + mloc) & 7)*8;    // ks=1 (chunk=4+quad)
    const int b0s = ((quad     + r) & 7)*8;
    const int b1s = ((quad + 4 + r) & 7)*8;

    f32x4 acc = (f32x4){0.f,0.f,0.f,0.f};
    const uint4 z4 = make_uint4(0,0,0,0);

    auto LD = [&](int tap, uint4& a0, uint4& a1, bool& va, bool& vb, uint4& bb) {
        const int dyy = (tap/K)*DIL - PAD;        // constants after full unroll
        const int dxx = (tap%K)*DIL - PAD;
        const int off = dyy*WW + dxx;
        {
            const int yy = pyA + dyy, xx = pxA + dxx;
            va = ((unsigned)yy < (unsigned)HH) && ((unsigned)xx < (unsigned)WW);
            a0 = *(const uint4*)(xb + (size_t)(va ? (pA + off) : 0)*64 + sc*8);
        }
        {
            const int yy = pyB + dyy, xx = pxB + dxx;
            vb = ((unsigned)yy < (unsigned)HH) && ((unsigned)xx < (unsigned)WW);
            a1 = *(const uint4*)(xb + (size_t)(vb ? (pB + off) : 0)*64 + sc*8);
        }
        if (bn < 16)
            bb = *(const uint4*)(wbase + ((size_t)tap*NP + bn)*64 + sc*8);
    };

    uint4 rA0 = z4, rA1 = z4, rB = z4;
    bool v0 = false, v1 = false;
    LD(0, rA0, rA1, v0, v1, rB);

    #pragma unroll
    for (int tap = 0; tap < KK; ++tap) {
        uint4 nA0 = z4, nA1 = z4, nB = z4;
        bool nv0 = false, nv1 = false;
        if (tap + 1 < KK) LD(tap + 1, nA0, nA1, nv0, nv1, nB);

        u16* A = &Ab[tap & 1][0];
        u16* Bq = &Bb[tap & 1][0];
        *(uint4*)(A + spx*64      + sslotA) = selz(v0, rA0);
        *(uint4*)(A + (spx+32)*64 + sslotA) = selz(v1, rA1);
        if (bn < 16) *(uint4*)(Bq + bn*64 + bslot) = rB;
        __syncthreads();

        const bf16x8 av0 = *(const bf16x8*)(A + arow + a0s);
        const bf16x8 av1 = *(const bf16x8*)(A + arow + a1s);
        const bf16x8 bv0 = *(const bf16x8*)(Bq + brow + b0s);
        const bf16x8 bv1 = *(const bf16x8*)(Bq + brow + b1s);
        acc = __builtin_amdgcn_mfma_f32_16x16x32_bf16(av0, bv0, acc, 0, 0, 0);
        acc = __builtin_amdgcn_mfma_f32_16x16x32_bf16(av1, bv1, acc, 0, 0, 0);

        rA0 = nA0; rA1 = nA1; rB = nB; v0 = nv0; v1 = nv1;
    }

    const int n = nt0*16 + r;
    if (n < COUT) {
        const float bv = bias[n];
        float* op = out + ((size_t)b*COUT + n)*HW + p0 + wave*16 + quad*4;
        #pragma unroll
        for (int r2 = 0; r2 < 4; ++r2) op[r2] = acc[r2] + bv;
    }
}

// ---------------------------------------------------------------------------
// Channel-last deformable bilinear + depthwise. Wave = one pixel, lane =
// channel; coalesced 128B corner loads; offsets wave-uniform.
// ---------------------------------------------------------------------------
template<int K, int DIL, int PAD>
__global__ __launch_bounds__(256)
void deform_cl_kernel(const u16* __restrict__ inT, const float* __restrict__ off,
                      const float* __restrict__ dwT, u16* __restrict__ outT) {
    constexpr int KK = K*K;
    const int gw   = __builtin_amdgcn_readfirstlane((blockIdx.x*256 + threadIdx.x) >> 6);
    const int lane = threadIdx.x & 63;
    const int p = gw % HW;
    const int b = gw / HW;
    const int h = p / WW, w = p % WW;

    const u16*   ib   = inT + (size_t)b*HW*64 + lane;
    const float* offp = off + (size_t)b*(2*KK)*HW + p;

    float acc = 0.f;
    #pragma unroll 7
    for (int k = 0; k < KK; ++k) {
        const float dy = offp[(size_t)(2*k  )*HW];
        const float dx = offp[(size_t)(2*k+1)*HW];
        const float py = (float)(h + (k/K)*DIL - PAD) + dy;
        const float px = (float)(w + (k%K)*DIL - PAD) + dx;
        const float y0f = floorf(py), x0f = floorf(px);
        const float wy1 = py - y0f,  wx1 = px - x0f;
        const float wy0 = 1.f - wy1, wx0 = 1.f - wx1;
        const int y0 = (int)y0f, x0 = (int)x0f;

        const int y0c = min(max(y0,   0), HH-1);
        const int y1c = min(max(y0+1, 0), HH-1);
        const int x0c = min(max(x0,   0), WW-1);
        const int x1c = min(max(x0+1, 0), WW-1);
        const float gy0 = wy0 * ((y0   >= 0 && y0   < HH) ? 1.f : 0.f);
        const float gy1 = wy1 * ((y0+1 >= 0 && y0+1 < HH) ? 1.f : 0.f);
        const float gx0 = wx0 * ((x0   >= 0 && x0   < WW) ? 1.f : 0.f);
        const float gx1 = wx1 * ((x0+1 >= 0 && x0+1 < WW) ? 1.f : 0.f);

        const int r0 = y0c*WW, r1 = y1c*WW;
        const float v00 = bf2f(ib[(size_t)(r0 + x0c)*64]);
        const float v01 = bf2f(ib[(size_t)(r0 + x1c)*64]);
        const float v10 = bf2f(ib[(size_t)(r1 + x0c)*64]);
        const float v11 = bf2f(ib[(size_t)(r1 + x1c)*64]);

        const float s = (v00*gx0 + v01*gx1)*gy0 + (v10*gx0 + v11*gx1)*gy1;
        acc += s * dwT[k*CC + lane];
    }
    outT[(size_t)gw*64 + lane] = f2bf(acc);
}

// ---------------------------------------------------------------------------
// Pointwise 1x1 via MFMA + fused residual multiply; wave = 16 px x 1 n-tile.
// ---------------------------------------------------------------------------
__global__ __launch_bounds__(256)
void pw_mfma_kernel(const u16* __restrict__ a2T, const u16* __restrict__ pwT,
                    const float* __restrict__ pb, const float* __restrict__ x,
                    float* __restrict__ out) {
    const int nm = HW/64;
    const int b  = blockIdx.x / nm;
    const int p0 = (blockIdx.x % nm)*64 + (threadIdx.x >> 6)*16;
    const int nt = blockIdx.y;
    const int lane = threadIdx.x & 63;
    const int r = lane & 15, quad = lane >> 4;

    const u16* ap = a2T + ((size_t)b*HW + p0 + r)*64 + quad*8;
    f32x4 acc = (f32x4){0.f,0.f,0.f,0.f};
    #pragma unroll
    for (int ks = 0; ks < 2; ++ks) {
        const bf16x8 av = *(const bf16x8*)(ap + ks*32);
        const bf16x8 bv = *(const bf16x8*)(pwT + ((size_t)(nt*16 + r))*64 + ks*32 + quad*8);
        acc = __builtin_amdgcn_mfma_f32_16x16x32_bf16(av, bv, acc, 0, 0, 0);
    }

    const int n = nt*16 + r;
    const float bv = pb[n];
    const size_t base = ((size_t)b*CC + n)*HW + p0 + quad*4;
    #pragma unroll
    for (int r2 = 0; r2 < 4; ++r2)
        out[base + r2] = x[base + r2] * (acc[r2] + bv);
}

// ======================= fallback fp32 kernels (low ws) =====================
template<int K, int DIL, int PAD, int COUT, int OCB>
__global__ __launch_bounds__(256)
void off_conv_sg_kernel(const float* __restrict__ in, const float* __restrict__ wgt,
                        const float* __restrict__ bias, float* __restrict__ out) {
    constexpr int KK = K*K;
    const int nOB = COUT / OCB;
    const int b   = blockIdx.x / nOB;
    const int oc0 = (blockIdx.x % nOB) * OCB;
    const int x   = threadIdx.x;
    const int h   = blockIdx.y*4 + threadIdx.y;

    float acc[OCB];
    #pragma unroll
    for (int o = 0; o < OCB; ++o) acc[o] = bias[oc0+o];

    const float* inb = in + (size_t)b*CC*HW;
    const float* wb  = wgt + (size_t)oc0*CC*KK;

    for (int ic = 0; ic < CC; ++ic) {
        const float* inp = inb + ic*HW;
        const float* wp  = wb + ic*KK;
        #pragma unroll
        for (int ky = 0; ky < K; ++ky) {
            const int  y  = h + ky*DIL - PAD;
            const bool yv = (y >= 0) && (y < HH);
            const int  yc = yv ? y : 0;
            const float* row = inp + yc*WW;
            #pragma unroll
            for (int kx = 0; kx < K; ++kx) {
                const int  xx = x + kx*DIL - PAD;
                const bool v  = yv && (xx >= 0) && (xx < WW);
                const int  xc = (xx < 0) ? 0 : ((xx >= WW) ? (WW-1) : xx);
                float val = row[xc];
                val = v ? val : 0.f;
                const int t = ky*K + kx;
                #pragma unroll
                for (int o = 0; o < OCB; ++o)
                    acc[o] += wp[(size_t)o*CC*KK + t] * val;
            }
        }
    }

    if (x >= WW) return;
    #pragma unroll
    for (int o = 0; o < OCB; ++o)
        out[((size_t)b*COUT + oc0 + o)*HW + h*WW + x] = acc[o];
}

template<int K, int DIL, int PAD>
__global__ __launch_bounds__(64)
void deform_dw_full_kernel(const float* __restrict__ in, const float* __restrict__ off,
                           const float* __restrict__ dw, float* __restrict__ out) {
    constexpr int KK = K*K;
    const int idx = blockIdx.x*64 + threadIdx.x;
    const int x = idx % WW;
    const int h = (idx / WW) % HH;
    const int c = (idx / HW) % CC;
    const int b = idx / (CC*HW);

    const float* inp  = in  + ((size_t)b*CC + c)*HW;
    const float* offp = off + (size_t)b*(2*KK)*HW + h*WW + x;
    const float* dwp  = dw  + c*KK;

    float acc = 0.f;
    #pragma unroll 7
    for (int k = 0; k < KK; ++k) {
        const float dy = offp[(2*k  )*HW];
        const float dx = offp[(2*k+1)*HW];
        const float py = (float)(h + (k/K)*DIL - PAD) + dy;
        const float px = (float)(x + (k%K)*DIL - PAD) + dx;
        const float y0f = floorf(py), x0f = floorf(px);
        const float wy1 = py - y0f,  wx1 = px - x0f;
        const float wy0 = 1.f - wy1, wx0 = 1.f - wx1;
        const int y0 = (int)y0f, x0 = (int)x0f;

        const int y0c = min(max(y0,   0), HH-1);
        const int y1c = min(max(y0+1, 0), HH-1);
        const int x0c = min(max(x0,   0), WW-1);
        const int x1c = min(max(x0+1, 0), WW-1);
        const float my0 = (y0   >= 0 && y0   < HH) ? 1.f : 0.f;
        const float my1 = (y0+1 >= 0 && y0+1 < HH) ? 1.f : 0.f;
        const float mx0 = (x0   >= 0 && x0   < WW) ? 1.f : 0.f;
        const float mx1 = (x0+1 >= 0 && x0+1 < WW) ? 1.f : 0.f;

        const float v00 = inp[y0c*WW + x0c];
        const float v01 = inp[y0c*WW + x1c];
        const float v10 = inp[y1c*WW + x0c];
        const float v11 = inp[y1c*WW + x1c];

        const float gx0 = wx0*mx0, gx1 = wx1*mx1;
        const float s = (v00*gx0 + v01*gx1) * (wy0*my0)
                      + (v10*gx0 + v11*gx1) * (wy1*my1);
        acc += s * dwp[k];
    }
    out[idx] = acc;
}

__global__ __launch_bounds__(256)
void pw_mul_kernel(const float* __restrict__ x, const float* __restrict__ a2,
                   const float* __restrict__ pw, const float* __restrict__ pb,
                   float* __restrict__ out) {
    constexpr int HW4 = HW/4;
    const int t = blockIdx.x*256 + threadIdx.x;
    if (t >= BB*CC*HW4) return;
    const int sp4 = t % HW4;
    const int oc  = (t / HW4) % CC;
    const int b   = t / (CC*HW4);

    const float4* ap = (const float4*)(a2 + (size_t)b*CC*HW) + sp4;
    const float4* wp4 = (const float4*)(pw + oc*CC);
    const float pbv = pb[oc];
    float4 acc = make_float4(pbv, pbv, pbv, pbv);
    #pragma unroll 4
    for (int ic4 = 0; ic4 < CC/4; ++ic4) {
        const float4 w = wp4[ic4];
        float4 a0 = ap[(ic4*4+0)*HW4];
        float4 a1 = ap[(ic4*4+1)*HW4];
        float4 a2v = ap[(ic4*4+2)*HW4];
        float4 a3 = ap[(ic4*4+3)*HW4];
        acc.x += w.x*a0.x + w.y*a1.x + w.z*a2v.x + w.w*a3.x;
        acc.y += w.x*a0.y + w.y*a1.y + w.z*a2v.y + w.w*a3.y;
        acc.z += w.x*a0.z + w.y*a1.z + w.z*a2v.z + w.w*a3.z;
        acc.w += w.x*a0.w + w.y*a1.w + w.z*a2v.w + w.w*a3.w;
    }
    const float4 xv = ((const float4*)x)[t];
    float4 r;
    r.x = xv.x*acc.x; r.y = xv.y*acc.y; r.z = xv.z*acc.z; r.w = xv.w*acc.w;
    ((float4*)out)[t] = r;
}

extern "C" void kernel_launch(void* const* d_in, const int* in_sizes, int n_in,
                              void* d_out, int out_size, void* d_ws, size_t ws_size,
                              hipStream_t stream) {
    const float* x      = (const float*)d_in[0];
    const float* off_w1 = (const float*)d_in[1];
    const float* off_b1 = (const float*)d_in[2];
    const float* dw_w1  = (const float*)d_in[3];
    const float* off_w2 = (const float*)d_in[4];
    const float* off_b2 = (const float*)d_in[5];
    const float* dw_w2  = (const float*)d_in[6];
    const float* pw_w   = (const float*)d_in[7];
    const float* pw_b   = (const float*)d_in[8];
    float* out = (float*)d_out;

    const size_t nF    = (size_t)BB*CC*HW;
    const size_t attnB = nF*sizeof(float);                 // 3,211,264
    const size_t off2B = (size_t)BB*98*HW*sizeof(float);   // 4,917,248
    const size_t chB   = (size_t)BB*HW*64*sizeof(u16);     // 1,605,632
    char* ws = (char*)d_ws;

    const int n    = (int)nF;
    const int dbl  = n/64;
    const int pbl  = (n/4 + 255)/256;
    dim3 cblk(64,4);
    dim3 rgrd1(BB*(50/5), HH/4);
    dim3 rgrd2(BB*(98/7), HH/4);
    const int tgrid = BB*(HW/64);            // 196
    dim3 cgrd1(tgrid, 4);                    // conv1: NP=64  -> 4 n-tiles
    dim3 cgrd2(tgrid, 7);                    // conv2: NP=112 -> 7 n-tiles
    dim3 pgrd(tgrid, 4);                     // pw
    const int dgrid = BB*HW/4;               // wave-per-pixel deform

    const size_t oOFF  = 0;
    const size_t oXT   = oOFF + off2B;
    const size_t oA1T  = oXT  + chB;
    const size_t oA2T  = oA1T + chB;
    const size_t oW1   = oA2T + chB;
    const size_t oW2   = oW1  + (size_t)R1*2;
    const size_t oPWT  = oW2  + (size_t)R2*2;
    const size_t oDW1  = oPWT + (size_t)R3*2;
    const size_t oDW2  = oDW1 + (size_t)R4*4;
    const size_t TOT   = oDW2 + (size_t)R5*4;

    if (ws_size >= TOT) {
        float* off_buf = (float*)(ws + oOFF);
        u16*   xT      = (u16*)(ws + oXT);
        u16*   a1T     = (u16*)(ws + oA1T);
        u16*   a2T     = (u16*)(ws + oA2T);
        u16*   w2t1    = (u16*)(ws + oW1);
        u16*   w2t2    = (u16*)(ws + oW2);
        u16*   pwT     = (u16*)(ws + oPWT);
        float* dwT1    = (float*)(ws + oDW1);
        float* dwT2    = (float*)(ws + oDW2);

        prep_all_kernel<<<(R1+R2+R3+R4+R5+255)/256, 256, 0, stream>>>(
            off_w1, off_w2, pw_w, dw_w1, dw_w2, w2t1, w2t2, pwT, dwT1, dwT2);
        transpose_bf16_kernel<<<tgrid, 256, 0, stream>>>(x, xT);

        conv_mfma_lds_kernel<5,1,2,50,64><<<cgrd1, 256, 0, stream>>>(xT, w2t1, off_b1, off_buf);
        deform_cl_kernel<5,1,2><<<dgrid, 256, 0, stream>>>(xT, off_buf, dwT1, a1T);

        conv_mfma_lds_kernel<7,3,9,98,112><<<cgrd2, 256, 0, stream>>>(a1T, w2t2, off_b2, off_buf);
        deform_cl_kernel<7,3,9><<<dgrid, 256, 0, stream>>>(a1T, off_buf, dwT2, a2T);

        pw_mfma_kernel<<<pgrd, 256, 0, stream>>>(a2T, pwT, pw_b, x, out);
    } else if (ws_size >= off2B + attnB) {
        float* off_buf = (float*)ws;
        float* attn1   = (float*)d_out;
        float* attn2   = (float*)(ws + off2B);
        off_conv_sg_kernel<5,1,2,50,5><<<rgrd1, cblk, 0, stream>>>(x, off_w1, off_b1, off_buf);
        deform_dw_full_kernel<5,1,2><<<dbl, 64, 0, stream>>>(x, off_buf, dw_w1, attn1);
        off_conv_sg_kernel<7,3,9,98,7><<<rgrd2, cblk, 0, stream>>>(attn1, off_w2, off_b2, off_buf);
        deform_dw_full_kernel<7,3,9><<<dbl, 64, 0, stream>>>(attn1, off_buf, dw_w2, attn2);
        pw_mul_kernel<<<pbl, 256, 0, stream>>>(x, attn2, pw_w, pw_b, out);
    } else {
        float* attn1 = (float*)d_out;
        float* attn2 = (float*)ws;
        float* off1  = (float*)ws;
        off_conv_sg_kernel<5,1,2,50,5><<<rgrd1, cblk, 0, stream>>>(x, off_w1, off_b1, off1);
        deform_dw_full_kernel<5,1,2><<<dbl, 64, 0, stream>>>(x, off1, dw_w1, attn1);
        float* off2 = (float*)(ws + attnB);
        off_conv_sg_kernel<7,3,9,98,7><<<rgrd2, cblk, 0, stream>>>(attn1, off_w2, off_b2, off2);
        deform_dw_full_kernel<7,3,9><<<dbl, 64, 0, stream>>>(attn1, off2, dw_w2, attn2);
        pw_mul_kernel<<<pbl, 256, 0, stream>>>(x, attn2, pw_w, pw_b, out);
    }
}

// Round 11
// 201.416 us; speedup vs baseline: 1.6620x; 1.0956x over previous
//
#include <hip/hip_runtime.h>

// Problem constants (from reference setup_inputs)
#define BB 4
#define CC 64
#define HH 56
#define WW 56
#define HW (HH*WW)

typedef unsigned short u16;
typedef __attribute__((ext_vector_type(8))) short bf16x8;
typedef __attribute__((ext_vector_type(4))) float f32x4;

__device__ __forceinline__ u16 f2bf(float f) {
    union { float f; unsigned u; } c; c.f = f;
    unsigned u = c.u;
    u = (u + 0x7FFFu + ((u >> 16) & 1u)) >> 16;   // RNE
    return (u16)u;
}
__device__ __forceinline__ float bf2f(u16 v) {
    union { unsigned u; float f; } c; c.u = ((unsigned)v) << 16;
    return c.f;
}

// ---------------------------------------------------------------------------
// Fused prep: all weight reshape/cast in ONE launch.
// ---------------------------------------------------------------------------
#define R1 102400
#define R2 351232
#define R3 4096
#define R4 1600
#define R5 3136
__global__ __launch_bounds__(256)
void prep_all_kernel(const float* __restrict__ ow1, const float* __restrict__ ow2,
                     const float* __restrict__ pw,  const float* __restrict__ dw1,
                     const float* __restrict__ dw2,
                     u16* __restrict__ w2t1, u16* __restrict__ w2t2,
                     u16* __restrict__ pwT, float* __restrict__ dwT1,
                     float* __restrict__ dwT2) {
    const int i = blockIdx.x*256 + threadIdx.x;
    if (i < R1) {
        const int ic = i & 63, n = (i >> 6) & 63, tap = i >> 12;
        w2t1[i] = f2bf((n < 50) ? ow1[((size_t)n*64 + ic)*25 + tap] : 0.f);
    } else if (i < R1+R2) {
        const int j = i - R1;
        const int ic = j & 63, n = (j >> 6) % 112, tap = j / 7168;
        w2t2[j] = f2bf((n < 98) ? ow2[((size_t)n*64 + ic)*49 + tap] : 0.f);
    } else if (i < R1+R2+R3) {
        const int j = i - (R1+R2);
        pwT[j] = f2bf(pw[j]);
    } else if (i < R1+R2+R3+R4) {
        const int j = i - (R1+R2+R3);
        const int c = j & 63, k = j >> 6;
        dwT1[j] = dw1[c*25 + k];
    } else if (i < R1+R2+R3+R4+R5) {
        const int j = i - (R1+R2+R3+R4);
        const int c = j & 63, k = j >> 6;
        dwT2[j] = dw2[c*49 + k];
    }
}

// ---------------------------------------------------------------------------
// Transpose + cast: in (B,CC,HW) fp32 -> out (B,HW,CC) bf16.
// ---------------------------------------------------------------------------
__global__ __launch_bounds__(256)
void transpose_bf16_kernel(const float* __restrict__ in, u16* __restrict__ out) {
    __shared__ u16 tile[64][72];
    const int blk = blockIdx.x;
    const int b   = blk / (HW/64);
    const int p0  = (blk % (HW/64))*64;
    const int t   = threadIdx.x;

    const int px  = t & 63, icq = t >> 6;
    const float* ip = in + ((size_t)b*CC + icq*16)*HW + p0 + px;
    #pragma unroll
    for (int i = 0; i < 16; ++i)
        tile[px][icq*16 + i] = f2bf(ip[(size_t)i*HW]);
    __syncthreads();

    const int px2 = t >> 2, g = t & 3;
    u16* op = out + ((size_t)b*HW + p0 + px2)*64 + g*16;
    const uint4* s = (const uint4*)&tile[px2][g*16];
    ((uint4*)op)[0] = s[0];
    ((uint4*)op)[1] = s[1];
}

__device__ __forceinline__ uint4 selz(bool v, uint4 a) {
    const uint4 z = make_uint4(0,0,0,0);
    return v ? a : z;
}

// ---------------------------------------------------------------------------
// LDS-staged MFMA implicit-GEMM conv (validated round 10; TA-optimized
// coalesced staging, XOR-swizzled conflict-free LDS, double-buffered,
// one barrier per tap).
// ---------------------------------------------------------------------------
template<int K, int DIL, int PAD, int COUT, int NP>
__global__ __launch_bounds__(256, 4)
void conv_mfma_lds_kernel(const u16* __restrict__ xT, const u16* __restrict__ w2t,
                          const float* __restrict__ bias, float* __restrict__ out) {
    constexpr int KK = K*K;
    __shared__ u16 Ab[2][64*64];
    __shared__ u16 Bb[2][16*64];

    const int nm   = HW/64;                       // 49
    const int b    = blockIdx.x / nm;
    const int p0   = (blockIdx.x % nm)*64;
    const int nt0  = blockIdx.y;
    const int t    = threadIdx.x;
    const int wave = t >> 6;
    const int lane = t & 63;

    const int spx = t >> 3;                       // 0..31
    const int sc  = t & 7;                        // chunk 0..7
    const int pA  = p0 + spx;
    const int pB  = p0 + spx + 32;
    const int pyA = pA / WW, pxA = pA % WW;
    const int pyB = pB / WW, pxB = pB % WW;
    const u16* xb = xT + (size_t)b*HW*64;
    const int sslotA = ((sc + spx) & 7)*8;
    const int bn  = t >> 3;
    const int bslot = ((sc + bn) & 7)*8;
    const u16* wbase = w2t + (size_t)nt0*16*64;

    const int r = lane & 15, quad = lane >> 4;
    const int mloc = wave*16 + r;
    const int arow = mloc*64, brow = r*64;
    const int a0s = ((quad     + mloc) & 7)*8;
    const int a1s = ((quad + 4 + mloc) & 7)*8;
    const int b0s = ((quad     + r) & 7)*8;
    const int b1s = ((quad + 4 + r) & 7)*8;

    f32x4 acc = (f32x4){0.f,0.f,0.f,0.f};
    const uint4 z4 = make_uint4(0,0,0,0);

    auto LD = [&](int tap, uint4& a0, uint4& a1, bool& va, bool& vb, uint4& bb) {
        const int dyy = (tap/K)*DIL - PAD;
        const int dxx = (tap%K)*DIL - PAD;
        const int off = dyy*WW + dxx;
        {
            const int yy = pyA + dyy, xx = pxA + dxx;
            va = ((unsigned)yy < (unsigned)HH) && ((unsigned)xx < (unsigned)WW);
            a0 = *(const uint4*)(xb + (size_t)(va ? (pA + off) : 0)*64 + sc*8);
        }
        {
            const int yy = pyB + dyy, xx = pxB + dxx;
            vb = ((unsigned)yy < (unsigned)HH) && ((unsigned)xx < (unsigned)WW);
            a1 = *(const uint4*)(xb + (size_t)(vb ? (pB + off) : 0)*64 + sc*8);
        }
        if (bn < 16)
            bb = *(const uint4*)(wbase + ((size_t)tap*NP + bn)*64 + sc*8);
    };

    uint4 rA0 = z4, rA1 = z4, rB = z4;
    bool v0 = false, v1 = false;
    LD(0, rA0, rA1, v0, v1, rB);

    #pragma unroll
    for (int tap = 0; tap < KK; ++tap) {
        uint4 nA0 = z4, nA1 = z4, nB = z4;
        bool nv0 = false, nv1 = false;
        if (tap + 1 < KK) LD(tap + 1, nA0, nA1, nv0, nv1, nB);

        u16* A = &Ab[tap & 1][0];
        u16* Bq = &Bb[tap & 1][0];
        *(uint4*)(A + spx*64      + sslotA) = selz(v0, rA0);
        *(uint4*)(A + (spx+32)*64 + sslotA) = selz(v1, rA1);
        if (bn < 16) *(uint4*)(Bq + bn*64 + bslot) = rB;
        __syncthreads();

        const bf16x8 av0 = *(const bf16x8*)(A + arow + a0s);
        const bf16x8 av1 = *(const bf16x8*)(A + arow + a1s);
        const bf16x8 bv0 = *(const bf16x8*)(Bq + brow + b0s);
        const bf16x8 bv1 = *(const bf16x8*)(Bq + brow + b1s);
        acc = __builtin_amdgcn_mfma_f32_16x16x32_bf16(av0, bv0, acc, 0, 0, 0);
        acc = __builtin_amdgcn_mfma_f32_16x16x32_bf16(av1, bv1, acc, 0, 0, 0);

        rA0 = nA0; rA1 = nA1; rB = nB; v0 = nv0; v1 = nv1;
    }

    const int n = nt0*16 + r;
    if (n < COUT) {
        const float bv = bias[n];
        float* op = out + ((size_t)b*COUT + n)*HW + p0 + wave*16 + quad*4;
        #pragma unroll
        for (int r2 = 0; r2 < 4; ++r2) op[r2] = acc[r2] + bv;
    }
}

// ---------------------------------------------------------------------------
// Two-phase channel-last deformable bilinear + depthwise.
// Phase 1: the block's 4 pixels x KK taps spread over 256 threads; each
// thread computes the 4 bilinear weights (same mask algebra as reference)
// and 4 clamped corner BYTE offsets, stored to LDS. One barrier.
// Phase 2: wave = pixel, lane = channel; per tap: float4+int4 LDS broadcast
// reads, 4 one-cache-line coalesced corner loads, 4 FMA + dw FMA. The
// wave-redundant coordinate math (~60 VALU/tap) is eliminated.
// ---------------------------------------------------------------------------
template<int K, int DIL, int PAD>
__global__ __launch_bounds__(256)
void deform_cl_kernel(const u16* __restrict__ inT, const float* __restrict__ off,
                      const float* __restrict__ dwT, u16* __restrict__ outT) {
    constexpr int KK = K*K;
    __shared__ float4 swt[4][KK];
    __shared__ int4   sat[4][KK];

    const int t  = threadIdx.x;
    const int p0 = blockIdx.x*4;          // 4 | HW -> all 4 pixels same batch
    const int b  = p0 / HW;
    const int pl0 = p0 - b*HW;
    const float* offb = off + (size_t)b*(2*KK)*HW;

    if (t < 4*KK) {
        const int pix = t / KK, k = t - pix*KK;
        const int pl  = pl0 + pix;
        const int h = pl / WW, w = pl % WW;
        const float dy = offb[(size_t)(2*k  )*HW + pl];
        const float dx = offb[(size_t)(2*k+1)*HW + pl];
        const float py = (float)(h + (k/K)*DIL - PAD) + dy;
        const float px = (float)(w + (k%K)*DIL - PAD) + dx;
        const float y0f = floorf(py), x0f = floorf(px);
        const float wy1 = py - y0f,  wx1 = px - x0f;
        const float wy0 = 1.f - wy1, wx0 = 1.f - wx1;
        const int y0 = (int)y0f, x0 = (int)x0f;

        const int y0c = min(max(y0,   0), HH-1);
        const int y1c = min(max(y0+1, 0), HH-1);
        const int x0c = min(max(x0,   0), WW-1);
        const int x1c = min(max(x0+1, 0), WW-1);
        const float gy0 = wy0 * ((y0   >= 0 && y0   < HH) ? 1.f : 0.f);
        const float gy1 = wy1 * ((y0+1 >= 0 && y0+1 < HH) ? 1.f : 0.f);
        const float gx0 = wx0 * ((x0   >= 0 && x0   < WW) ? 1.f : 0.f);
        const float gx1 = wx1 * ((x0+1 >= 0 && x0+1 < WW) ? 1.f : 0.f);

        swt[pix][k] = make_float4(gy0*gx0, gy0*gx1, gy1*gx0, gy1*gx1);
        const int r0 = y0c*WW, r1 = y1c*WW;
        sat[pix][k] = make_int4((r0 + x0c) << 7, (r0 + x1c) << 7,
                                (r1 + x0c) << 7, (r1 + x1c) << 7);
    }
    __syncthreads();

    const int wave = t >> 6, lane = t & 63;
    const char* ib = (const char*)(inT + (size_t)b*HW*64) + lane*2;

    float acc = 0.f;
    #pragma unroll 7
    for (int k = 0; k < KK; ++k) {
        const float4 wv = swt[wave][k];
        const int4   av = sat[wave][k];
        const float v00 = bf2f(*(const u16*)(ib + av.x));
        const float v01 = bf2f(*(const u16*)(ib + av.y));
        const float v10 = bf2f(*(const u16*)(ib + av.z));
        const float v11 = bf2f(*(const u16*)(ib + av.w));
        const float s = v00*wv.x + v01*wv.y + v10*wv.z + v11*wv.w;
        acc += s * dwT[k*CC + lane];
    }
    outT[(size_t)(p0 + wave)*64 + lane] = f2bf(acc);
}

// ---------------------------------------------------------------------------
// Pointwise 1x1 via MFMA + fused residual multiply; wave = 16 px x 1 n-tile.
// ---------------------------------------------------------------------------
__global__ __launch_bounds__(256)
void pw_mfma_kernel(const u16* __restrict__ a2T, const u16* __restrict__ pwT,
                    const float* __restrict__ pb, const float* __restrict__ x,
                    float* __restrict__ out) {
    const int nm = HW/64;
    const int b  = blockIdx.x / nm;
    const int p0 = (blockIdx.x % nm)*64 + (threadIdx.x >> 6)*16;
    const int nt = blockIdx.y;
    const int lane = threadIdx.x & 63;
    const int r = lane & 15, quad = lane >> 4;

    const u16* ap = a2T + ((size_t)b*HW + p0 + r)*64 + quad*8;
    f32x4 acc = (f32x4){0.f,0.f,0.f,0.f};
    #pragma unroll
    for (int ks = 0; ks < 2; ++ks) {
        const bf16x8 av = *(const bf16x8*)(ap + ks*32);
        const bf16x8 bv = *(const bf16x8*)(pwT + ((size_t)(nt*16 + r))*64 + ks*32 + quad*8);
        acc = __builtin_amdgcn_mfma_f32_16x16x32_bf16(av, bv, acc, 0, 0, 0);
    }

    const int n = nt*16 + r;
    const float bv = pb[n];
    const size_t base = ((size_t)b*CC + n)*HW + p0 + quad*4;
    #pragma unroll
    for (int r2 = 0; r2 < 4; ++r2)
        out[base + r2] = x[base + r2] * (acc[r2] + bv);
}

// ======================= fallback fp32 kernels (low ws) =====================
template<int K, int DIL, int PAD, int COUT, int OCB>
__global__ __launch_bounds__(256)
void off_conv_sg_kernel(const float* __restrict__ in, const float* __restrict__ wgt,
                        const float* __restrict__ bias, float* __restrict__ out) {
    constexpr int KK = K*K;
    const int nOB = COUT / OCB;
    const int b   = blockIdx.x / nOB;
    const int oc0 = (blockIdx.x % nOB) * OCB;
    const int x   = threadIdx.x;
    const int h   = blockIdx.y*4 + threadIdx.y;

    float acc[OCB];
    #pragma unroll
    for (int o = 0; o < OCB; ++o) acc[o] = bias[oc0+o];

    const float* inb = in + (size_t)b*CC*HW;
    const float* wb  = wgt + (size_t)oc0*CC*KK;

    for (int ic = 0; ic < CC; ++ic) {
        const float* inp = inb + ic*HW;
        const float* wp  = wb + ic*KK;
        #pragma unroll
        for (int ky = 0; ky < K; ++ky) {
            const int  y  = h + ky*DIL - PAD;
            const bool yv = (y >= 0) && (y < HH);
            const int  yc = yv ? y : 0;
            const float* row = inp + yc*WW;
            #pragma unroll
            for (int kx = 0; kx < K; ++kx) {
                const int  xx = x + kx*DIL - PAD;
                const bool v  = yv && (xx >= 0) && (xx < WW);
                const int  xc = (xx < 0) ? 0 : ((xx >= WW) ? (WW-1) : xx);
                float val = row[xc];
                val = v ? val : 0.f;
                const int t = ky*K + kx;
                #pragma unroll
                for (int o = 0; o < OCB; ++o)
                    acc[o] += wp[(size_t)o*CC*KK + t] * val;
            }
        }
    }

    if (x >= WW) return;
    #pragma unroll
    for (int o = 0; o < OCB; ++o)
        out[((size_t)b*COUT + oc0 + o)*HW + h*WW + x] = acc[o];
}

template<int K, int DIL, int PAD>
__global__ __launch_bounds__(64)
void deform_dw_full_kernel(const float* __restrict__ in, const float* __restrict__ off,
                           const float* __restrict__ dw, float* __restrict__ out) {
    constexpr int KK = K*K;
    const int idx = blockIdx.x*64 + threadIdx.x;
    const int x = idx % WW;
    const int h = (idx / WW) % HH;
    const int c = (idx / HW) % CC;
    const int b = idx / (CC*HW);

    const float* inp  = in  + ((size_t)b*CC + c)*HW;
    const float* offp = off + (size_t)b*(2*KK)*HW + h*WW + x;
    const float* dwp  = dw  + c*KK;

    float acc = 0.f;
    #pragma unroll 7
    for (int k = 0; k < KK; ++k) {
        const float dy = offp[(2*k  )*HW];
        const float dx = offp[(2*k+1)*HW];
        const float py = (float)(h + (k/K)*DIL - PAD) + dy;
        const float px = (float)(x + (k%K)*DIL - PAD) + dx;
        const float y0f = floorf(py), x0f = floorf(px);
        const float wy1 = py - y0f,  wx1 = px - x0f;
        const float wy0 = 1.f - wy1, wx0 = 1.f - wx1;
        const int y0 = (int)y0f, x0 = (int)x0f;

        const int y0c = min(max(y0,   0), HH-1);
        const int y1c = min(max(y0+1, 0), HH-1);
        const int x0c = min(max(x0,   0), WW-1);
        const int x1c = min(max(x0+1, 0), WW-1);
        const float my0 = (y0   >= 0 && y0   < HH) ? 1.f : 0.f;
        const float my1 = (y0+1 >= 0 && y0+1 < HH) ? 1.f : 0.f;
        const float mx0 = (x0   >= 0 && x0   < WW) ? 1.f : 0.f;
        const float mx1 = (x0+1 >= 0 && x0+1 < WW) ? 1.f : 0.f;

        const float v00 = inp[y0c*WW + x0c];
        const float v01 = inp[y0c*WW + x1c];
        const float v10 = inp[y1c*WW + x0c];
        const float v11 = inp[y1c*WW + x1c];

        const float gx0 = wx0*mx0, gx1 = wx1*mx1;
        const float s = (v00*gx0 + v01*gx1) * (wy0*my0)
                      + (v10*gx0 + v11*gx1) * (wy1*my1);
        acc += s * dwp[k];
    }
    out[idx] = acc;
}

__global__ __launch_bounds__(256)
void pw_mul_kernel(const float* __restrict__ x, const float* __restrict__ a2,
                   const float* __restrict__ pw, const float* __restrict__ pb,
                   float* __restrict__ out) {
    constexpr int HW4 = HW/4;
    const int t = blockIdx.x*256 + threadIdx.x;
    if (t >= BB*CC*HW4) return;
    const int sp4 = t % HW4;
    const int oc  = (t / HW4) % CC;
    const int b   = t / (CC*HW4);

    const float4* ap = (const float4*)(a2 + (size_t)b*CC*HW) + sp4;
    const float4* wp4 = (const float4*)(pw + oc*CC);
    const float pbv = pb[oc];
    float4 acc = make_float4(pbv, pbv, pbv, pbv);
    #pragma unroll 4
    for (int ic4 = 0; ic4 < CC/4; ++ic4) {
        const float4 w = wp4[ic4];
        float4 a0 = ap[(ic4*4+0)*HW4];
        float4 a1 = ap[(ic4*4+1)*HW4];
        float4 a2v = ap[(ic4*4+2)*HW4];
        float4 a3 = ap[(ic4*4+3)*HW4];
        acc.x += w.x*a0.x + w.y*a1.x + w.z*a2v.x + w.w*a3.x;
        acc.y += w.x*a0.y + w.y*a1.y + w.z*a2v.y + w.w*a3.y;
        acc.z += w.x*a0.z + w.y*a1.z + w.z*a2v.z + w.w*a3.z;
        acc.w += w.x*a0.w + w.y*a1.w + w.z*a2v.w + w.w*a3.w;
    }
    const float4 xv = ((const float4*)x)[t];
    float4 r;
    r.x = xv.x*acc.x; r.y = xv.y*acc.y; r.z = xv.z*acc.z; r.w = xv.w*acc.w;
    ((float4*)out)[t] = r;
}

extern "C" void kernel_launch(void* const* d_in, const int* in_sizes, int n_in,
                              void* d_out, int out_size, void* d_ws, size_t ws_size,
                              hipStream_t stream) {
    const float* x      = (const float*)d_in[0];
    const float* off_w1 = (const float*)d_in[1];
    const float* off_b1 = (const float*)d_in[2];
    const float* dw_w1  = (const float*)d_in[3];
    const float* off_w2 = (const float*)d_in[4];
    const float* off_b2 = (const float*)d_in[5];
    const float* dw_w2  = (const float*)d_in[6];
    const float* pw_w   = (const float*)d_in[7];
    const float* pw_b   = (const float*)d_in[8];
    float* out = (float*)d_out;

    const size_t nF    = (size_t)BB*CC*HW;
    const size_t attnB = nF*sizeof(float);                 // 3,211,264
    const size_t off2B = (size_t)BB*98*HW*sizeof(float);   // 4,917,248
    const size_t chB   = (size_t)BB*HW*64*sizeof(u16);     // 1,605,632
    char* ws = (char*)d_ws;

    const int n    = (int)nF;
    const int dbl  = n/64;
    const int pbl  = (n/4 + 255)/256;
    dim3 cblk(64,4);
    dim3 rgrd1(BB*(50/5), HH/4);
    dim3 rgrd2(BB*(98/7), HH/4);
    const int tgrid = BB*(HW/64);            // 196
    dim3 cgrd1(tgrid, 4);                    // conv1: NP=64  -> 4 n-tiles
    dim3 cgrd2(tgrid, 7);                    // conv2: NP=112 -> 7 n-tiles
    dim3 pgrd(tgrid, 4);                     // pw
    const int dgrid = BB*HW/4;               // 4 pixels per block

    const size_t oOFF  = 0;
    const size_t oXT   = oOFF + off2B;
    const size_t oA1T  = oXT  + chB;
    const size_t oA2T  = oA1T + chB;
    const size_t oW1   = oA2T + chB;
    const size_t oW2   = oW1  + (size_t)R1*2;
    const size_t oPWT  = oW2  + (size_t)R2*2;
    const size_t oDW1  = oPWT + (size_t)R3*2;
    const size_t oDW2  = oDW1 + (size_t)R4*4;
    const size_t TOT   = oDW2 + (size_t)R5*4;

    if (ws_size >= TOT) {
        float* off_buf = (float*)(ws + oOFF);
        u16*   xT      = (u16*)(ws + oXT);
        u16*   a1T     = (u16*)(ws + oA1T);
        u16*   a2T     = (u16*)(ws + oA2T);
        u16*   w2t1    = (u16*)(ws + oW1);
        u16*   w2t2    = (u16*)(ws + oW2);
        u16*   pwT     = (u16*)(ws + oPWT);
        float* dwT1    = (float*)(ws + oDW1);
        float* dwT2    = (float*)(ws + oDW2);

        prep_all_kernel<<<(R1+R2+R3+R4+R5+255)/256, 256, 0, stream>>>(
            off_w1, off_w2, pw_w, dw_w1, dw_w2, w2t1, w2t2, pwT, dwT1, dwT2);
        transpose_bf16_kernel<<<tgrid, 256, 0, stream>>>(x, xT);

        conv_mfma_lds_kernel<5,1,2,50,64><<<cgrd1, 256, 0, stream>>>(xT, w2t1, off_b1, off_buf);
        deform_cl_kernel<5,1,2><<<dgrid, 256, 0, stream>>>(xT, off_buf, dwT1, a1T);

        conv_mfma_lds_kernel<7,3,9,98,112><<<cgrd2, 256, 0, stream>>>(a1T, w2t2, off_b2, off_buf);
        deform_cl_kernel<7,3,9><<<dgrid, 256, 0, stream>>>(a1T, off_buf, dwT2, a2T);

        pw_mfma_kernel<<<pgrd, 256, 0, stream>>>(a2T, pwT, pw_b, x, out);
    } else if (ws_size >= off2B + attnB) {
        float* off_buf = (float*)ws;
        float* attn1   = (float*)d_out;
        float* attn2   = (float*)(ws + off2B);
        off_conv_sg_kernel<5,1,2,50,5><<<rgrd1, cblk, 0, stream>>>(x, off_w1, off_b1, off_buf);
        deform_dw_full_kernel<5,1,2><<<dbl, 64, 0, stream>>>(x, off_buf, dw_w1, attn1);
        off_conv_sg_kernel<7,3,9,98,7><<<rgrd2, cblk, 0, stream>>>(attn1, off_w2, off_b2, off_buf);
        deform_dw_full_kernel<7,3,9><<<dbl, 64, 0, stream>>>(attn1, off_buf, dw_w2, attn2);
        pw_mul_kernel<<<pbl, 256, 0, stream>>>(x, attn2, pw_w, pw_b, out);
    } else {
        float* attn1 = (float*)d_out;
        float* attn2 = (float*)ws;
        float* off1  = (float*)ws;
        off_conv_sg_kernel<5,1,2,50,5><<<rgrd1, cblk, 0, stream>>>(x, off_w1, off_b1, off1);
        deform_dw_full_kernel<5,1,2><<<dbl, 64, 0, stream>>>(x, off1, dw_w1, attn1);
        float* off2 = (float*)(ws + attnB);
        off_conv_sg_kernel<7,3,9,98,7><<<rgrd2, cblk, 0, stream>>>(attn1, off_w2, off_b2, off2);
        deform_dw_full_kernel<7,3,9><<<dbl, 64, 0, stream>>>(attn1, off2, dw_w2, attn2);
        pw_mul_kernel<<<pbl, 256, 0, stream>>>(x, attn2, pw_w, pw_b, out);
    }
}

// Round 12
// 175.882 us; speedup vs baseline: 1.9033x; 1.1452x over previous
//
#include <hip/hip_runtime.h>

// Problem constants (from reference setup_inputs)
#define BB 4
#define CC 64
#define HH 56
#define WW 56
#define HW (HH*WW)

typedef unsigned short u16;
typedef __attribute__((ext_vector_type(8))) short bf16x8;
typedef __attribute__((ext_vector_type(4))) float f32x4;

__device__ __forceinline__ u16 f2bf(float f) {
    union { float f; unsigned u; } c; c.f = f;
    unsigned u = c.u;
    u = (u + 0x7FFFu + ((u >> 16) & 1u)) >> 16;   // RNE
    return (u16)u;
}
__device__ __forceinline__ float bf2f(u16 v) {
    union { unsigned u; float f; } c; c.u = ((unsigned)v) << 16;
    return c.f;
}

// ---------------------------------------------------------------------------
// Fused prep. w2t2 padded to NP=128 (zeros for n>=98) so conv NTW=2 B-staging
// never reads OOB.
// ---------------------------------------------------------------------------
#define R1 102400
#define R2 401408
#define R3 4096
#define R4 1600
#define R5 3136
__global__ __launch_bounds__(256)
void prep_all_kernel(const float* __restrict__ ow1, const float* __restrict__ ow2,
                     const float* __restrict__ pw,  const float* __restrict__ dw1,
                     const float* __restrict__ dw2,
                     u16* __restrict__ w2t1, u16* __restrict__ w2t2,
                     u16* __restrict__ pwT, float* __restrict__ dwT1,
                     float* __restrict__ dwT2) {
    const int i = blockIdx.x*256 + threadIdx.x;
    if (i < R1) {
        const int ic = i & 63, n = (i >> 6) & 63, tap = i >> 12;
        w2t1[i] = f2bf((n < 50) ? ow1[((size_t)n*64 + ic)*25 + tap] : 0.f);
    } else if (i < R1+R2) {
        const int j = i - R1;
        const int ic = j & 63, n = (j >> 6) & 127, tap = j >> 13;
        w2t2[j] = f2bf((n < 98) ? ow2[((size_t)n*64 + ic)*49 + tap] : 0.f);
    } else if (i < R1+R2+R3) {
        const int j = i - (R1+R2);
        pwT[j] = f2bf(pw[j]);
    } else if (i < R1+R2+R3+R4) {
        const int j = i - (R1+R2+R3);
        const int c = j & 63, k = j >> 6;
        dwT1[j] = dw1[c*25 + k];
    } else if (i < R1+R2+R3+R4+R5) {
        const int j = i - (R1+R2+R3+R4);
        const int c = j & 63, k = j >> 6;
        dwT2[j] = dw2[c*49 + k];
    }
}

// ---------------------------------------------------------------------------
// Transpose + cast: in (B,CC,HW) fp32 -> out (B,HW,CC) bf16.
// ---------------------------------------------------------------------------
__global__ __launch_bounds__(256)
void transpose_bf16_kernel(const float* __restrict__ in, u16* __restrict__ out) {
    __shared__ u16 tile[64][72];
    const int blk = blockIdx.x;
    const int b   = blk / (HW/64);
    const int p0  = (blk % (HW/64))*64;
    const int t   = threadIdx.x;

    const int px  = t & 63, icq = t >> 6;
    const float* ip = in + ((size_t)b*CC + icq*16)*HW + p0 + px;
    #pragma unroll
    for (int i = 0; i < 16; ++i)
        tile[px][icq*16 + i] = f2bf(ip[(size_t)i*HW]);
    __syncthreads();

    const int px2 = t >> 2, g = t & 3;
    u16* op = out + ((size_t)b*HW + p0 + px2)*64 + g*16;
    const uint4* s = (const uint4*)&tile[px2][g*16];
    ((uint4*)op)[0] = s[0];
    ((uint4*)op)[1] = s[1];
}

__device__ __forceinline__ uint4 selz(bool v, uint4 a) {
    const uint4 z = make_uint4(0,0,0,0);
    return v ? a : z;
}

// ---------------------------------------------------------------------------
// LDS-staged MFMA implicit-GEMM conv (R10-validated structure), now NTW=2
// (32 output channels per block -> ~32% fewer staging line-requests, 2x MFMA
// per barrier) and TRANSPOSED output: off (B,HW,NPAD) fp32, so the deform
// kernel's offset reads are contiguous per pixel.
// ---------------------------------------------------------------------------
template<int K, int DIL, int PAD, int COUT, int NP, int NPAD, int NTW>
__global__ __launch_bounds__(256, 4)
void conv_mfma_lds_kernel(const u16* __restrict__ xT, const u16* __restrict__ w2t,
                          const float* __restrict__ bias, float* __restrict__ out) {
    constexpr int KK = K*K;
    constexpr int BROWS = 16*NTW;
    __shared__ u16 Ab[2][64*64];
    __shared__ u16 Bb[2][BROWS*64];

    const int nm   = HW/64;                       // 49
    const int b    = blockIdx.x / nm;
    const int p0   = (blockIdx.x % nm)*64;
    const int nt0  = blockIdx.y;
    const int t    = threadIdx.x;
    const int wave = t >> 6;
    const int lane = t & 63;

    const int spx = t >> 3;                       // 0..31
    const int sc  = t & 7;                        // chunk 0..7
    const int pA  = p0 + spx;
    const int pB  = p0 + spx + 32;
    const int pyA = pA / WW, pxA = pA % WW;
    const int pyB = pB / WW, pxB = pB % WW;
    const u16* xb = xT + (size_t)b*HW*64;
    const int sslotA = ((sc + spx) & 7)*8;
    const int bn  = t >> 3;                       // 0..31 (B row, BROWS<=32)
    const int bslot = ((sc + bn) & 7)*8;
    const u16* wbase = w2t + (size_t)nt0*BROWS*64;

    const int r = lane & 15, quad = lane >> 4;
    const int mloc = wave*16 + r;
    const int arow = mloc*64;
    const int a0s = ((quad     + mloc) & 7)*8;
    const int a1s = ((quad + 4 + mloc) & 7)*8;
    const int b0s = ((quad     + r) & 7)*8;
    const int b1s = ((quad + 4 + r) & 7)*8;

    f32x4 acc[NTW];
    #pragma unroll
    for (int h = 0; h < NTW; ++h) acc[h] = (f32x4){0.f,0.f,0.f,0.f};
    const uint4 z4 = make_uint4(0,0,0,0);

    auto LD = [&](int tap, uint4& a0, uint4& a1, bool& va, bool& vb, uint4& bb) {
        const int dyy = (tap/K)*DIL - PAD;
        const int dxx = (tap%K)*DIL - PAD;
        const int off = dyy*WW + dxx;
        {
            const int yy = pyA + dyy, xx = pxA + dxx;
            va = ((unsigned)yy < (unsigned)HH) && ((unsigned)xx < (unsigned)WW);
            a0 = *(const uint4*)(xb + (size_t)(va ? (pA + off) : 0)*64 + sc*8);
        }
        {
            const int yy = pyB + dyy, xx = pxB + dxx;
            vb = ((unsigned)yy < (unsigned)HH) && ((unsigned)xx < (unsigned)WW);
            a1 = *(const uint4*)(xb + (size_t)(vb ? (pB + off) : 0)*64 + sc*8);
        }
        if (BROWS == 32 || bn < BROWS)
            bb = *(const uint4*)(wbase + ((size_t)tap*NP + bn)*64 + sc*8);
    };

    uint4 rA0 = z4, rA1 = z4, rB = z4;
    bool v0 = false, v1 = false;
    LD(0, rA0, rA1, v0, v1, rB);

    #pragma unroll
    for (int tap = 0; tap < KK; ++tap) {
        uint4 nA0 = z4, nA1 = z4, nB = z4;
        bool nv0 = false, nv1 = false;
        if (tap + 1 < KK) LD(tap + 1, nA0, nA1, nv0, nv1, nB);

        u16* A  = &Ab[tap & 1][0];
        u16* Bq = &Bb[tap & 1][0];
        *(uint4*)(A + spx*64      + sslotA) = selz(v0, rA0);
        *(uint4*)(A + (spx+32)*64 + sslotA) = selz(v1, rA1);
        if (BROWS == 32 || bn < BROWS) *(uint4*)(Bq + bn*64 + bslot) = rB;
        __syncthreads();

        const bf16x8 av0 = *(const bf16x8*)(A + arow + a0s);
        const bf16x8 av1 = *(const bf16x8*)(A + arow + a1s);
        #pragma unroll
        for (int h = 0; h < NTW; ++h) {
            const int brow = (h*16 + r)*64;       // slot unchanged: 16h%8==0
            const bf16x8 bv0 = *(const bf16x8*)(Bq + brow + b0s);
            const bf16x8 bv1 = *(const bf16x8*)(Bq + brow + b1s);
            acc[h] = __builtin_amdgcn_mfma_f32_16x16x32_bf16(av0, bv0, acc[h], 0, 0, 0);
            acc[h] = __builtin_amdgcn_mfma_f32_16x16x32_bf16(av1, bv1, acc[h], 0, 0, 0);
        }

        rA0 = nA0; rA1 = nA1; rB = nB; v0 = nv0; v1 = nv1;
    }

    // Transposed epilogue: out[(b*HW + p)*NPAD + n], p = p0+wave*16+quad*4+r2.
    #pragma unroll
    for (int h = 0; h < NTW; ++h) {
        const int n = nt0*BROWS + h*16 + r;
        if (n < COUT) {
            const float bv = bias[n];
            float* op = out + ((size_t)b*HW + p0 + wave*16 + quad*4)*NPAD + n;
            #pragma unroll
            for (int r2 = 0; r2 < 4; ++r2) op[(size_t)r2*NPAD] = acc[h][r2] + bv;
        }
    }
}

// ---------------------------------------------------------------------------
// Two-phase channel-last deformable bilinear + depthwise.
// Offsets now (B,HW,NPAD): phase-1 reads are contiguous per pixel. dw weights
// staged in LDS (no per-tap global lines). XCD-contiguous block swizzle.
// ---------------------------------------------------------------------------
template<int K, int DIL, int PAD, int NPAD>
__global__ __launch_bounds__(256)
void deform_cl_kernel(const u16* __restrict__ inT, const float* __restrict__ offT,
                      const float* __restrict__ dwT, u16* __restrict__ outT) {
    constexpr int KK = K*K;
    __shared__ float4 swt[4][KK];
    __shared__ int4   sat[4][KK];
    __shared__ float  sdw[KK*64];

    const int t = threadIdx.x;
    const int nb8 = (BB*HW/4) >> 3;               // 392
    const int blk0 = blockIdx.x;
    const int blk = (blk0 & 7)*nb8 + (blk0 >> 3); // XCD-contiguous pixels
    const int p0 = blk*4;
    const int b  = p0 / HW;
    const int pl0 = p0 - b*HW;

    for (int i = t; i < KK*64; i += 256) sdw[i] = dwT[i];

    if (t < 4*KK) {
        const int pix = t / KK, k = t - pix*KK;
        const int pl  = pl0 + pix;
        const int h = pl / WW, w = pl % WW;
        const float* orow = offT + ((size_t)b*HW + pl)*NPAD;
        const float dy = orow[2*k];
        const float dx = orow[2*k+1];
        const float py = (float)(h + (k/K)*DIL - PAD) + dy;
        const float px = (float)(w + (k%K)*DIL - PAD) + dx;
        const float y0f = floorf(py), x0f = floorf(px);
        const float wy1 = py - y0f,  wx1 = px - x0f;
        const float wy0 = 1.f - wy1, wx0 = 1.f - wx1;
        const int y0 = (int)y0f, x0 = (int)x0f;

        const int y0c = min(max(y0,   0), HH-1);
        const int y1c = min(max(y0+1, 0), HH-1);
        const int x0c = min(max(x0,   0), WW-1);
        const int x1c = min(max(x0+1, 0), WW-1);
        const float gy0 = wy0 * ((y0   >= 0 && y0   < HH) ? 1.f : 0.f);
        const float gy1 = wy1 * ((y0+1 >= 0 && y0+1 < HH) ? 1.f : 0.f);
        const float gx0 = wx0 * ((x0   >= 0 && x0   < WW) ? 1.f : 0.f);
        const float gx1 = wx1 * ((x0+1 >= 0 && x0+1 < WW) ? 1.f : 0.f);

        swt[pix][k] = make_float4(gy0*gx0, gy0*gx1, gy1*gx0, gy1*gx1);
        const int r0 = y0c*WW, r1 = y1c*WW;
        sat[pix][k] = make_int4((r0 + x0c) << 7, (r0 + x1c) << 7,
                                (r1 + x0c) << 7, (r1 + x1c) << 7);
    }
    __syncthreads();

    const int wave = t >> 6, lane = t & 63;
    const char* ib = (const char*)(inT + (size_t)b*HW*64) + lane*2;

    float acc = 0.f;
    #pragma unroll 7
    for (int k = 0; k < KK; ++k) {
        const float4 wv = swt[wave][k];
        const int4   av = sat[wave][k];
        const float v00 = bf2f(*(const u16*)(ib + av.x));
        const float v01 = bf2f(*(const u16*)(ib + av.y));
        const float v10 = bf2f(*(const u16*)(ib + av.z));
        const float v11 = bf2f(*(const u16*)(ib + av.w));
        const float s = v00*wv.x + v01*wv.y + v10*wv.z + v11*wv.w;
        acc += s * sdw[k*64 + lane];
    }
    outT[(size_t)(p0 + wave)*64 + lane] = f2bf(acc);
}

// ---------------------------------------------------------------------------
// Pointwise 1x1 via MFMA + fused residual multiply; wave = 16 px x 1 n-tile.
// ---------------------------------------------------------------------------
__global__ __launch_bounds__(256)
void pw_mfma_kernel(const u16* __restrict__ a2T, const u16* __restrict__ pwT,
                    const float* __restrict__ pb, const float* __restrict__ x,
                    float* __restrict__ out) {
    const int nm = HW/64;
    const int b  = blockIdx.x / nm;
    const int p0 = (blockIdx.x % nm)*64 + (threadIdx.x >> 6)*16;
    const int nt = blockIdx.y;
    const int lane = threadIdx.x & 63;
    const int r = lane & 15, quad = lane >> 4;

    const u16* ap = a2T + ((size_t)b*HW + p0 + r)*64 + quad*8;
    f32x4 acc = (f32x4){0.f,0.f,0.f,0.f};
    #pragma unroll
    for (int ks = 0; ks < 2; ++ks) {
        const bf16x8 av = *(const bf16x8*)(ap + ks*32);
        const bf16x8 bv = *(const bf16x8*)(pwT + ((size_t)(nt*16 + r))*64 + ks*32 + quad*8);
        acc = __builtin_amdgcn_mfma_f32_16x16x32_bf16(av, bv, acc, 0, 0, 0);
    }

    const int n = nt*16 + r;
    const float bv = pb[n];
    const size_t base = ((size_t)b*CC + n)*HW + p0 + quad*4;
    #pragma unroll
    for (int r2 = 0; r2 < 4; ++r2)
        out[base + r2] = x[base + r2] * (acc[r2] + bv);
}

// ======================= fallback fp32 kernels (low ws) =====================
template<int K, int DIL, int PAD, int COUT, int OCB>
__global__ __launch_bounds__(256)
void off_conv_sg_kernel(const float* __restrict__ in, const float* __restrict__ wgt,
                        const float* __restrict__ bias, float* __restrict__ out) {
    constexpr int KK = K*K;
    const int nOB = COUT / OCB;
    const int b   = blockIdx.x / nOB;
    const int oc0 = (blockIdx.x % nOB) * OCB;
    const int x   = threadIdx.x;
    const int h   = blockIdx.y*4 + threadIdx.y;

    float acc[OCB];
    #pragma unroll
    for (int o = 0; o < OCB; ++o) acc[o] = bias[oc0+o];

    const float* inb = in + (size_t)b*CC*HW;
    const float* wb  = wgt + (size_t)oc0*CC*KK;

    for (int ic = 0; ic < CC; ++ic) {
        const float* inp = inb + ic*HW;
        const float* wp  = wb + ic*KK;
        #pragma unroll
        for (int ky = 0; ky < K; ++ky) {
            const int  y  = h + ky*DIL - PAD;
            const bool yv = (y >= 0) && (y < HH);
            const int  yc = yv ? y : 0;
            const float* row = inp + yc*WW;
            #pragma unroll
            for (int kx = 0; kx < K; ++kx) {
                const int  xx = x + kx*DIL - PAD;
                const bool v  = yv && (xx >= 0) && (xx < WW);
                const int  xc = (xx < 0) ? 0 : ((xx >= WW) ? (WW-1) : xx);
                float val = row[xc];
                val = v ? val : 0.f;
                const int t = ky*K + kx;
                #pragma unroll
                for (int o = 0; o < OCB; ++o)
                    acc[o] += wp[(size_t)o*CC*KK + t] * val;
            }
        }
    }

    if (x >= WW) return;
    #pragma unroll
    for (int o = 0; o < OCB; ++o)
        out[((size_t)b*COUT + oc0 + o)*HW + h*WW + x] = acc[o];
}

template<int K, int DIL, int PAD>
__global__ __launch_bounds__(64)
void deform_dw_full_kernel(const float* __restrict__ in, const float* __restrict__ off,
                           const float* __restrict__ dw, float* __restrict__ out) {
    constexpr int KK = K*K;
    const int idx = blockIdx.x*64 + threadIdx.x;
    const int x = idx % WW;
    const int h = (idx / WW) % HH;
    const int c = (idx / HW) % CC;
    const int b = idx / (CC*HW);

    const float* inp  = in  + ((size_t)b*CC + c)*HW;
    const float* offp = off + (size_t)b*(2*KK)*HW + h*WW + x;
    const float* dwp  = dw  + c*KK;

    float acc = 0.f;
    #pragma unroll 7
    for (int k = 0; k < KK; ++k) {
        const float dy = offp[(2*k  )*HW];
        const float dx = offp[(2*k+1)*HW];
        const float py = (float)(h + (k/K)*DIL - PAD) + dy;
        const float px = (float)(x + (k%K)*DIL - PAD) + dx;
        const float y0f = floorf(py), x0f = floorf(px);
        const float wy1 = py - y0f,  wx1 = px - x0f;
        const float wy0 = 1.f - wy1, wx0 = 1.f - wx1;
        const int y0 = (int)y0f, x0 = (int)x0f;

        const int y0c = min(max(y0,   0), HH-1);
        const int y1c = min(max(y0+1, 0), HH-1);
        const int x0c = min(max(x0,   0), WW-1);
        const int x1c = min(max(x0+1, 0), WW-1);
        const float my0 = (y0   >= 0 && y0   < HH) ? 1.f : 0.f;
        const float my1 = (y0+1 >= 0 && y0+1 < HH) ? 1.f : 0.f;
        const float mx0 = (x0   >= 0 && x0   < WW) ? 1.f : 0.f;
        const float mx1 = (x0+1 >= 0 && x0+1 < WW) ? 1.f : 0.f;

        const float v00 = inp[y0c*WW + x0c];
        const float v01 = inp[y0c*WW + x1c];
        const float v10 = inp[y1c*WW + x0c];
        const float v11 = inp[y1c*WW + x1c];

        const float gx0 = wx0*mx0, gx1 = wx1*mx1;
        const float s = (v00*gx0 + v01*gx1) * (wy0*my0)
                      + (v10*gx0 + v11*gx1) * (wy1*my1);
        acc += s * dwp[k];
    }
    out[idx] = acc;
}

__global__ __launch_bounds__(256)
void pw_mul_kernel(const float* __restrict__ x, const float* __restrict__ a2,
                   const float* __restrict__ pw, const float* __restrict__ pb,
                   float* __restrict__ out) {
    constexpr int HW4 = HW/4;
    const int t = blockIdx.x*256 + threadIdx.x;
    if (t >= BB*CC*HW4) return;
    const int sp4 = t % HW4;
    const int oc  = (t / HW4) % CC;
    const int b   = t / (CC*HW4);

    const float4* ap = (const float4*)(a2 + (size_t)b*CC*HW) + sp4;
    const float4* wp4 = (const float4*)(pw + oc*CC);
    const float pbv = pb[oc];
    float4 acc = make_float4(pbv, pbv, pbv, pbv);
    #pragma unroll 4
    for (int ic4 = 0; ic4 < CC/4; ++ic4) {
        const float4 w = wp4[ic4];
        float4 a0 = ap[(ic4*4+0)*HW4];
        float4 a1 = ap[(ic4*4+1)*HW4];
        float4 a2v = ap[(ic4*4+2)*HW4];
        float4 a3 = ap[(ic4*4+3)*HW4];
        acc.x += w.x*a0.x + w.y*a1.x + w.z*a2v.x + w.w*a3.x;
        acc.y += w.x*a0.y + w.y*a1.y + w.z*a2v.y + w.w*a3.y;
        acc.z += w.x*a0.z + w.y*a1.z + w.z*a2v.z + w.w*a3.z;
        acc.w += w.x*a0.w + w.y*a1.w + w.z*a2v.w + w.w*a3.w;
    }
    const float4 xv = ((const float4*)x)[t];
    float4 r;
    r.x = xv.x*acc.x; r.y = xv.y*acc.y; r.z = xv.z*acc.z; r.w = xv.w*acc.w;
    ((float4*)out)[t] = r;
}

extern "C" void kernel_launch(void* const* d_in, const int* in_sizes, int n_in,
                              void* d_out, int out_size, void* d_ws, size_t ws_size,
                              hipStream_t stream) {
    const float* x      = (const float*)d_in[0];
    const float* off_w1 = (const float*)d_in[1];
    const float* off_b1 = (const float*)d_in[2];
    const float* dw_w1  = (const float*)d_in[3];
    const float* off_w2 = (const float*)d_in[4];
    const float* off_b2 = (const float*)d_in[5];
    const float* dw_w2  = (const float*)d_in[6];
    const float* pw_w   = (const float*)d_in[7];
    const float* pw_b   = (const float*)d_in[8];
    float* out = (float*)d_out;

    const size_t nF    = (size_t)BB*CC*HW;
    const size_t attnB = nF*sizeof(float);                 // 3,211,264
    const size_t off2B = (size_t)BB*98*HW*sizeof(float);   // 4,917,248 (fallback)
    const size_t offTB = (size_t)BB*HW*112*sizeof(float);  // 5,619,712 (transposed)
    const size_t chB   = (size_t)BB*HW*64*sizeof(u16);     // 1,605,632
    char* ws = (char*)d_ws;

    const int n    = (int)nF;
    const int dbl  = n/64;
    const int pbl  = (n/4 + 255)/256;
    dim3 cblk(64,4);
    dim3 rgrd1(BB*(50/5), HH/4);
    dim3 rgrd2(BB*(98/7), HH/4);
    const int tgrid = BB*(HW/64);            // 196
    dim3 cgrd1(tgrid, 2);                    // conv1: 64 n / 32 per block
    dim3 cgrd2(tgrid, 4);                    // conv2: 128 n / 32 per block
    dim3 pgrd(tgrid, 4);                     // pw
    const int dgrid = BB*HW/4;               // 3136 (4 pixels per block)

    const size_t oOFF  = 0;
    const size_t oXT   = oOFF + offTB;
    const size_t oA1T  = oXT  + chB;
    const size_t oA2T  = oA1T + chB;
    const size_t oW1   = oA2T + chB;
    const size_t oW2   = oW1  + (size_t)R1*2;
    const size_t oPWT  = oW2  + (size_t)R2*2;
    const size_t oDW1  = oPWT + (size_t)R3*2;
    const size_t oDW2  = oDW1 + (size_t)R4*4;
    const size_t TOT   = oDW2 + (size_t)R5*4;   // ~11.47 MB

    if (ws_size >= TOT) {
        float* off_buf = (float*)(ws + oOFF);
        u16*   xT      = (u16*)(ws + oXT);
        u16*   a1T     = (u16*)(ws + oA1T);
        u16*   a2T     = (u16*)(ws + oA2T);
        u16*   w2t1    = (u16*)(ws + oW1);
        u16*   w2t2    = (u16*)(ws + oW2);
        u16*   pwT     = (u16*)(ws + oPWT);
        float* dwT1    = (float*)(ws + oDW1);
        float* dwT2    = (float*)(ws + oDW2);

        prep_all_kernel<<<(R1+R2+R3+R4+R5+255)/256, 256, 0, stream>>>(
            off_w1, off_w2, pw_w, dw_w1, dw_w2, w2t1, w2t2, pwT, dwT1, dwT2);
        transpose_bf16_kernel<<<tgrid, 256, 0, stream>>>(x, xT);

        conv_mfma_lds_kernel<5,1,2,50,64,64,2><<<cgrd1, 256, 0, stream>>>(xT, w2t1, off_b1, off_buf);
        deform_cl_kernel<5,1,2,64><<<dgrid, 256, 0, stream>>>(xT, off_buf, dwT1, a1T);

        conv_mfma_lds_kernel<7,3,9,98,128,112,2><<<cgrd2, 256, 0, stream>>>(a1T, w2t2, off_b2, off_buf);
        deform_cl_kernel<7,3,9,112><<<dgrid, 256, 0, stream>>>(a1T, off_buf, dwT2, a2T);

        pw_mfma_kernel<<<pgrd, 256, 0, stream>>>(a2T, pwT, pw_b, x, out);
    } else if (ws_size >= off2B + attnB) {
        float* off_buf = (float*)ws;
        float* attn1   = (float*)d_out;
        float* attn2   = (float*)(ws + off2B);
        off_conv_sg_kernel<5,1,2,50,5><<<rgrd1, cblk, 0, stream>>>(x, off_w1, off_b1, off_buf);
        deform_dw_full_kernel<5,1,2><<<dbl, 64, 0, stream>>>(x, off_buf, dw_w1, attn1);
        off_conv_sg_kernel<7,3,9,98,7><<<rgrd2, cblk, 0, stream>>>(attn1, off_w2, off_b2, off_buf);
        deform_dw_full_kernel<7,3,9><<<dbl, 64, 0, stream>>>(attn1, off_buf, dw_w2, attn2);
        pw_mul_kernel<<<pbl, 256, 0, stream>>>(x, attn2, pw_w, pw_b, out);
    } else {
        float* attn1 = (float*)d_out;
        float* attn2 = (float*)ws;
        float* off1  = (float*)ws;
        off_conv_sg_kernel<5,1,2,50,5><<<rgrd1, cblk, 0, stream>>>(x, off_w1, off_b1, off1);
        deform_dw_full_kernel<5,1,2><<<dbl, 64, 0, stream>>>(x, off1, dw_w1, attn1);
        float* off2 = (float*)(ws + attnB);
        off_conv_sg_kernel<7,3,9,98,7><<<rgrd2, cblk, 0, stream>>>(attn1, off_w2, off_b2, off2);
        deform_dw_full_kernel<7,3,9><<<dbl, 64, 0, stream>>>(attn1, off2, dw_w2, attn2);
        pw_mul_kernel<<<pbl, 256, 0, stream>>>(x, attn2, pw_w, pw_b, out);
    }
}

// Round 13
// 158.946 us; speedup vs baseline: 2.1061x; 1.1066x over previous
//
#include <hip/hip_runtime.h>

// Problem constants (from reference setup_inputs)
#define BB 4
#define CC 64
#define HH 56
#define WW 56
#define HW (HH*WW)

typedef unsigned short u16;
typedef unsigned int u32;
typedef __attribute__((ext_vector_type(8))) short bf16x8;
typedef __attribute__((ext_vector_type(4))) float f32x4;

__device__ __forceinline__ u16 f2bf(float f) {
    union { float f; unsigned u; } c; c.f = f;
    unsigned u = c.u;
    u = (u + 0x7FFFu + ((u >> 16) & 1u)) >> 16;   // RNE
    return (u16)u;
}
__device__ __forceinline__ float bf2f(u16 v) {
    union { unsigned u; float f; } c; c.u = ((unsigned)v) << 16;
    return c.f;
}
__device__ __forceinline__ float lo_f(u32 u) {   // bf16 pair -> lo fp32
    union { unsigned u; float f; } c; c.u = u << 16; return c.f;
}
__device__ __forceinline__ float hi_f(u32 u) {   // bf16 pair -> hi fp32
    union { unsigned u; float f; } c; c.u = u & 0xffff0000u; return c.f;
}

// ---------------------------------------------------------------------------
// Fused prep + input transpose in ONE launch.
// blocks [0, TGRID): transpose x (B,CC,HW) fp32 -> xT (B,HW,CC) bf16.
// blocks [TGRID, ...): weight reshape/cast (w2t2 padded to NP=128).
// ---------------------------------------------------------------------------
#define R1 102400
#define R2 401408
#define R3 4096
#define R4 1600
#define R5 3136
#define TGRID (BB*(HW/64))          // 196
#define PREPN (R1+R2+R3+R4+R5)
__global__ __launch_bounds__(256)
void prep_tr_kernel(const float* __restrict__ x,
                    const float* __restrict__ ow1, const float* __restrict__ ow2,
                    const float* __restrict__ pw,  const float* __restrict__ dw1,
                    const float* __restrict__ dw2,
                    u16* __restrict__ xT,
                    u16* __restrict__ w2t1, u16* __restrict__ w2t2,
                    u16* __restrict__ pwT, float* __restrict__ dwT1,
                    float* __restrict__ dwT2) {
    __shared__ u16 tile[64][72];
    const int t = threadIdx.x;
    if (blockIdx.x < TGRID) {
        const int blk = blockIdx.x;
        const int b   = blk / (HW/64);
        const int p0  = (blk % (HW/64))*64;
        const int px  = t & 63, icq = t >> 6;
        const float* ip = x + ((size_t)b*CC + icq*16)*HW + p0 + px;
        #pragma unroll
        for (int i = 0; i < 16; ++i)
            tile[px][icq*16 + i] = f2bf(ip[(size_t)i*HW]);
        __syncthreads();
        const int px2 = t >> 2, g = t & 3;
        u16* op = xT + ((size_t)b*HW + p0 + px2)*64 + g*16;
        const uint4* s = (const uint4*)&tile[px2][g*16];
        ((uint4*)op)[0] = s[0];
        ((uint4*)op)[1] = s[1];
        return;
    }
    const int i = (blockIdx.x - TGRID)*256 + t;
    if (i < R1) {
        const int ic = i & 63, n = (i >> 6) & 63, tap = i >> 12;
        w2t1[i] = f2bf((n < 50) ? ow1[((size_t)n*64 + ic)*25 + tap] : 0.f);
    } else if (i < R1+R2) {
        const int j = i - R1;
        const int ic = j & 63, n = (j >> 6) & 127, tap = j >> 13;
        w2t2[j] = f2bf((n < 98) ? ow2[((size_t)n*64 + ic)*49 + tap] : 0.f);
    } else if (i < R1+R2+R3) {
        const int j = i - (R1+R2);
        pwT[j] = f2bf(pw[j]);
    } else if (i < R1+R2+R3+R4) {
        const int j = i - (R1+R2+R3);
        const int c = j & 63, k = j >> 6;
        dwT1[j] = dw1[c*25 + k];
    } else if (i < R1+R2+R3+R4+R5) {
        const int j = i - (R1+R2+R3+R4);
        const int c = j & 63, k = j >> 6;
        dwT2[j] = dw2[c*49 + k];
    }
}

__device__ __forceinline__ uint4 selz(bool v, uint4 a) {
    const uint4 z = make_uint4(0,0,0,0);
    return v ? a : z;
}

// ---------------------------------------------------------------------------
// LDS-staged MFMA implicit-GEMM conv (R10/R12-validated). NTW=2, transposed
// output off (B,HW,NPAD) fp32 so deform's offset reads are contiguous.
// ---------------------------------------------------------------------------
template<int K, int DIL, int PAD, int COUT, int NP, int NPAD, int NTW>
__global__ __launch_bounds__(256, 4)
void conv_mfma_lds_kernel(const u16* __restrict__ xT, const u16* __restrict__ w2t,
                          const float* __restrict__ bias, float* __restrict__ out) {
    constexpr int KK = K*K;
    constexpr int BROWS = 16*NTW;
    __shared__ u16 Ab[2][64*64];
    __shared__ u16 Bb[2][BROWS*64];

    const int nm   = HW/64;                       // 49
    const int b    = blockIdx.x / nm;
    const int p0   = (blockIdx.x % nm)*64;
    const int nt0  = blockIdx.y;
    const int t    = threadIdx.x;
    const int wave = t >> 6;
    const int lane = t & 63;

    const int spx = t >> 3;                       // 0..31
    const int sc  = t & 7;                        // chunk 0..7
    const int pA  = p0 + spx;
    const int pB  = p0 + spx + 32;
    const int pyA = pA / WW, pxA = pA % WW;
    const int pyB = pB / WW, pxB = pB % WW;
    const u16* xb = xT + (size_t)b*HW*64;
    const int sslotA = ((sc + spx) & 7)*8;
    const int bn  = t >> 3;                       // 0..31
    const int bslot = ((sc + bn) & 7)*8;
    const u16* wbase = w2t + (size_t)nt0*BROWS*64;

    const int r = lane & 15, quad = lane >> 4;
    const int mloc = wave*16 + r;
    const int arow = mloc*64;
    const int a0s = ((quad     + mloc) & 7)*8;
    const int a1s = ((quad + 4 + mloc) & 7)*8;
    const int b0s = ((quad     + r) & 7)*8;
    const int b1s = ((quad + 4 + r) & 7)*8;

    f32x4 acc[NTW];
    #pragma unroll
    for (int h = 0; h < NTW; ++h) acc[h] = (f32x4){0.f,0.f,0.f,0.f};
    const uint4 z4 = make_uint4(0,0,0,0);

    auto LD = [&](int tap, uint4& a0, uint4& a1, bool& va, bool& vb, uint4& bb) {
        const int dyy = (tap/K)*DIL - PAD;
        const int dxx = (tap%K)*DIL - PAD;
        const int off = dyy*WW + dxx;
        {
            const int yy = pyA + dyy, xx = pxA + dxx;
            va = ((unsigned)yy < (unsigned)HH) && ((unsigned)xx < (unsigned)WW);
            a0 = *(const uint4*)(xb + (size_t)(va ? (pA + off) : 0)*64 + sc*8);
        }
        {
            const int yy = pyB + dyy, xx = pxB + dxx;
            vb = ((unsigned)yy < (unsigned)HH) && ((unsigned)xx < (unsigned)WW);
            a1 = *(const uint4*)(xb + (size_t)(vb ? (pB + off) : 0)*64 + sc*8);
        }
        if (BROWS == 32 || bn < BROWS)
            bb = *(const uint4*)(wbase + ((size_t)tap*NP + bn)*64 + sc*8);
    };

    uint4 rA0 = z4, rA1 = z4, rB = z4;
    bool v0 = false, v1 = false;
    LD(0, rA0, rA1, v0, v1, rB);

    #pragma unroll
    for (int tap = 0; tap < KK; ++tap) {
        uint4 nA0 = z4, nA1 = z4, nB = z4;
        bool nv0 = false, nv1 = false;
        if (tap + 1 < KK) LD(tap + 1, nA0, nA1, nv0, nv1, nB);

        u16* A  = &Ab[tap & 1][0];
        u16* Bq = &Bb[tap & 1][0];
        *(uint4*)(A + spx*64      + sslotA) = selz(v0, rA0);
        *(uint4*)(A + (spx+32)*64 + sslotA) = selz(v1, rA1);
        if (BROWS == 32 || bn < BROWS) *(uint4*)(Bq + bn*64 + bslot) = rB;
        __syncthreads();

        const bf16x8 av0 = *(const bf16x8*)(A + arow + a0s);
        const bf16x8 av1 = *(const bf16x8*)(A + arow + a1s);
        #pragma unroll
        for (int h = 0; h < NTW; ++h) {
            const int brow = (h*16 + r)*64;
            const bf16x8 bv0 = *(const bf16x8*)(Bq + brow + b0s);
            const bf16x8 bv1 = *(const bf16x8*)(Bq + brow + b1s);
            acc[h] = __builtin_amdgcn_mfma_f32_16x16x32_bf16(av0, bv0, acc[h], 0, 0, 0);
            acc[h] = __builtin_amdgcn_mfma_f32_16x16x32_bf16(av1, bv1, acc[h], 0, 0, 0);
        }

        rA0 = nA0; rA1 = nA1; rB = nB; v0 = nv0; v1 = nv1;
    }

    #pragma unroll
    for (int h = 0; h < NTW; ++h) {
        const int n = nt0*BROWS + h*16 + r;
        if (n < COUT) {
            const float bv = bias[n];
            float* op = out + ((size_t)b*HW + p0 + wave*16 + quad*4)*NPAD + n;
            #pragma unroll
            for (int r2 = 0; r2 < 4; ++r2) op[(size_t)r2*NPAD] = acc[h][r2] + bv;
        }
    }
}

// ---------------------------------------------------------------------------
// Two-phase deform, 2 channels/lane. Wave = 2 pixels x 32 lanes x 2 ch:
// u32 corner loads (half the VMEM instrs of R12), bf16-pair unpack is
// 1 shift + 1 mask, weight math on float pairs (packable). Block = 8 pixels.
// Phase 1 unchanged math (4 bilinear weights + 4 clamped byte offsets -> LDS).
// dw staged in LDS as [k][c] (float2 per lane). XCD-contiguous swizzle.
// ---------------------------------------------------------------------------
template<int K, int DIL, int PAD, int NPAD>
__global__ __launch_bounds__(256)
void deform_cl_kernel(const u16* __restrict__ inT, const float* __restrict__ offT,
                      const float* __restrict__ dwT, u16* __restrict__ outT) {
    constexpr int KK = K*K;
    __shared__ float4 swt[8][KK];
    __shared__ int4   sat[8][KK];
    __shared__ float  sdw[KK*64];

    const int t = threadIdx.x;
    const int nb8 = (BB*HW/8) >> 3;               // 196
    const int blk0 = blockIdx.x;
    const int blk = (blk0 & 7)*nb8 + (blk0 >> 3); // XCD-contiguous pixels
    const int p0 = blk*8;
    const int b  = p0 / HW;                       // 8 | HW -> same batch
    const int pl0 = p0 - b*HW;

    for (int i = t; i < KK*64; i += 256) sdw[i] = dwT[i];

    for (int i = t; i < 8*KK; i += 256) {
        const int pix = i / KK, k = i - pix*KK;
        const int pl  = pl0 + pix;
        const int h = pl / WW, w = pl % WW;
        const float* orow = offT + ((size_t)b*HW + pl)*NPAD;
        const float dy = orow[2*k];
        const float dx = orow[2*k+1];
        const float py = (float)(h + (k/K)*DIL - PAD) + dy;
        const float px = (float)(w + (k%K)*DIL - PAD) + dx;
        const float y0f = floorf(py), x0f = floorf(px);
        const float wy1 = py - y0f,  wx1 = px - x0f;
        const float wy0 = 1.f - wy1, wx0 = 1.f - wx1;
        const int y0 = (int)y0f, x0 = (int)x0f;

        const int y0c = min(max(y0,   0), HH-1);
        const int y1c = min(max(y0+1, 0), HH-1);
        const int x0c = min(max(x0,   0), WW-1);
        const int x1c = min(max(x0+1, 0), WW-1);
        const float gy0 = wy0 * ((y0   >= 0 && y0   < HH) ? 1.f : 0.f);
        const float gy1 = wy1 * ((y0+1 >= 0 && y0+1 < HH) ? 1.f : 0.f);
        const float gx0 = wx0 * ((x0   >= 0 && x0   < WW) ? 1.f : 0.f);
        const float gx1 = wx1 * ((x0+1 >= 0 && x0+1 < WW) ? 1.f : 0.f);

        swt[pix][k] = make_float4(gy0*gx0, gy0*gx1, gy1*gx0, gy1*gx1);
        const int r0 = y0c*WW, r1 = y1c*WW;
        sat[pix][k] = make_int4((r0 + x0c) << 7, (r0 + x1c) << 7,
                                (r1 + x0c) << 7, (r1 + x1c) << 7);
    }
    __syncthreads();

    const int wave = t >> 6, lane = t & 63;
    const int pixl = 2*wave + (lane >> 5);        // 0..7 (half-wave = pixel)
    const int chp  = lane & 31;                   // channel pair 0..31
    const char* ib = (const char*)(inT + (size_t)b*HW*64) + chp*4;

    float accx = 0.f, accy = 0.f;
    #pragma unroll 7
    for (int k = 0; k < KK; ++k) {
        const float4 wv = swt[pixl][k];
        const int4   av = sat[pixl][k];
        const u32 c00 = *(const u32*)(ib + av.x);
        const u32 c01 = *(const u32*)(ib + av.y);
        const u32 c10 = *(const u32*)(ib + av.z);
        const u32 c11 = *(const u32*)(ib + av.w);
        const float sx = lo_f(c00)*wv.x + lo_f(c01)*wv.y + lo_f(c10)*wv.z + lo_f(c11)*wv.w;
        const float sy = hi_f(c00)*wv.x + hi_f(c01)*wv.y + hi_f(c10)*wv.z + hi_f(c11)*wv.w;
        const float2 dw2 = *(const float2*)&sdw[k*64 + 2*chp];
        accx += sx * dw2.x;
        accy += sy * dw2.y;
    }
    const u32 o = (u32)f2bf(accx) | ((u32)f2bf(accy) << 16);
    *(u32*)((char*)outT + (size_t)(p0 + pixl)*128 + chp*4) = o;
}

// ---------------------------------------------------------------------------
// Pointwise 1x1 via MFMA + fused residual multiply; wave = 16 px x 1 n-tile.
// ---------------------------------------------------------------------------
__global__ __launch_bounds__(256)
void pw_mfma_kernel(const u16* __restrict__ a2T, const u16* __restrict__ pwT,
                    const float* __restrict__ pb, const float* __restrict__ x,
                    float* __restrict__ out) {
    const int nm = HW/64;
    const int b  = blockIdx.x / nm;
    const int p0 = (blockIdx.x % nm)*64 + (threadIdx.x >> 6)*16;
    const int nt = blockIdx.y;
    const int lane = threadIdx.x & 63;
    const int r = lane & 15, quad = lane >> 4;

    const u16* ap = a2T + ((size_t)b*HW + p0 + r)*64 + quad*8;
    f32x4 acc = (f32x4){0.f,0.f,0.f,0.f};
    #pragma unroll
    for (int ks = 0; ks < 2; ++ks) {
        const bf16x8 av = *(const bf16x8*)(ap + ks*32);
        const bf16x8 bv = *(const bf16x8*)(pwT + ((size_t)(nt*16 + r))*64 + ks*32 + quad*8);
        acc = __builtin_amdgcn_mfma_f32_16x16x32_bf16(av, bv, acc, 0, 0, 0);
    }

    const int n = nt*16 + r;
    const float bv = pb[n];
    const size_t base = ((size_t)b*CC + n)*HW + p0 + quad*4;
    #pragma unroll
    for (int r2 = 0; r2 < 4; ++r2)
        out[base + r2] = x[base + r2] * (acc[r2] + bv);
}

// ======================= fallback fp32 kernels (low ws) =====================
template<int K, int DIL, int PAD, int COUT, int OCB>
__global__ __launch_bounds__(256)
void off_conv_sg_kernel(const float* __restrict__ in, const float* __restrict__ wgt,
                        const float* __restrict__ bias, float* __restrict__ out) {
    constexpr int KK = K*K;
    const int nOB = COUT / OCB;
    const int b   = blockIdx.x / nOB;
    const int oc0 = (blockIdx.x % nOB) * OCB;
    const int x   = threadIdx.x;
    const int h   = blockIdx.y*4 + threadIdx.y;

    float acc[OCB];
    #pragma unroll
    for (int o = 0; o < OCB; ++o) acc[o] = bias[oc0+o];

    const float* inb = in + (size_t)b*CC*HW;
    const float* wb  = wgt + (size_t)oc0*CC*KK;

    for (int ic = 0; ic < CC; ++ic) {
        const float* inp = inb + ic*HW;
        const float* wp  = wb + ic*KK;
        #pragma unroll
        for (int ky = 0; ky < K; ++ky) {
            const int  y  = h + ky*DIL - PAD;
            const bool yv = (y >= 0) && (y < HH);
            const int  yc = yv ? y : 0;
            const float* row = inp + yc*WW;
            #pragma unroll
            for (int kx = 0; kx < K; ++kx) {
                const int  xx = x + kx*DIL - PAD;
                const bool v  = yv && (xx >= 0) && (xx < WW);
                const int  xc = (xx < 0) ? 0 : ((xx >= WW) ? (WW-1) : xx);
                float val = row[xc];
                val = v ? val : 0.f;
                const int t = ky*K + kx;
                #pragma unroll
                for (int o = 0; o < OCB; ++o)
                    acc[o] += wp[(size_t)o*CC*KK + t] * val;
            }
        }
    }

    if (x >= WW) return;
    #pragma unroll
    for (int o = 0; o < OCB; ++o)
        out[((size_t)b*COUT + oc0 + o)*HW + h*WW + x] = acc[o];
}

template<int K, int DIL, int PAD>
__global__ __launch_bounds__(64)
void deform_dw_full_kernel(const float* __restrict__ in, const float* __restrict__ off,
                           const float* __restrict__ dw, float* __restrict__ out) {
    constexpr int KK = K*K;
    const int idx = blockIdx.x*64 + threadIdx.x;
    const int x = idx % WW;
    const int h = (idx / WW) % HH;
    const int c = (idx / HW) % CC;
    const int b = idx / (CC*HW);

    const float* inp  = in  + ((size_t)b*CC + c)*HW;
    const float* offp = off + (size_t)b*(2*KK)*HW + h*WW + x;
    const float* dwp  = dw  + c*KK;

    float acc = 0.f;
    #pragma unroll 7
    for (int k = 0; k < KK; ++k) {
        const float dy = offp[(2*k  )*HW];
        const float dx = offp[(2*k+1)*HW];
        const float py = (float)(h + (k/K)*DIL - PAD) + dy;
        const float px = (float)(x + (k%K)*DIL - PAD) + dx;
        const float y0f = floorf(py), x0f = floorf(px);
        const float wy1 = py - y0f,  wx1 = px - x0f;
        const float wy0 = 1.f - wy1, wx0 = 1.f - wx1;
        const int y0 = (int)y0f, x0 = (int)x0f;

        const int y0c = min(max(y0,   0), HH-1);
        const int y1c = min(max(y0+1, 0), HH-1);
        const int x0c = min(max(x0,   0), WW-1);
        const int x1c = min(max(x0+1, 0), WW-1);
        const float my0 = (y0   >= 0 && y0   < HH) ? 1.f : 0.f;
        const float my1 = (y0+1 >= 0 && y0+1 < HH) ? 1.f : 0.f;
        const float mx0 = (x0   >= 0 && x0   < WW) ? 1.f : 0.f;
        const float mx1 = (x0+1 >= 0 && x0+1 < WW) ? 1.f : 0.f;

        const float v00 = inp[y0c*WW + x0c];
        const float v01 = inp[y0c*WW + x1c];
        const float v10 = inp[y1c*WW + x0c];
        const float v11 = inp[y1c*WW + x1c];

        const float gx0 = wx0*mx0, gx1 = wx1*mx1;
        const float s = (v00*gx0 + v01*gx1) * (wy0*my0)
                      + (v10*gx0 + v11*gx1) * (wy1*my1);
        acc += s * dwp[k];
    }
    out[idx] = acc;
}

__global__ __launch_bounds__(256)
void pw_mul_kernel(const float* __restrict__ x, const float* __restrict__ a2,
                   const float* __restrict__ pw, const float* __restrict__ pb,
                   float* __restrict__ out) {
    constexpr int HW4 = HW/4;
    const int t = blockIdx.x*256 + threadIdx.x;
    if (t >= BB*CC*HW4) return;
    const int sp4 = t % HW4;
    const int oc  = (t / HW4) % CC;
    const int b   = t / (CC*HW4);

    const float4* ap = (const float4*)(a2 + (size_t)b*CC*HW) + sp4;
    const float4* wp4 = (const float4*)(pw + oc*CC);
    const float pbv = pb[oc];
    float4 acc = make_float4(pbv, pbv, pbv, pbv);
    #pragma unroll 4
    for (int ic4 = 0; ic4 < CC/4; ++ic4) {
        const float4 w = wp4[ic4];
        float4 a0 = ap[(ic4*4+0)*HW4];
        float4 a1 = ap[(ic4*4+1)*HW4];
        float4 a2v = ap[(ic4*4+2)*HW4];
        float4 a3 = ap[(ic4*4+3)*HW4];
        acc.x += w.x*a0.x + w.y*a1.x + w.z*a2v.x + w.w*a3.x;
        acc.y += w.x*a0.y + w.y*a1.y + w.z*a2v.y + w.w*a3.y;
        acc.z += w.x*a0.z + w.y*a1.z + w.z*a2v.z + w.w*a3.z;
        acc.w += w.x*a0.w + w.y*a1.w + w.z*a2v.w + w.w*a3.w;
    }
    const float4 xv = ((const float4*)x)[t];
    float4 r;
    r.x = xv.x*acc.x; r.y = xv.y*acc.y; r.z = xv.z*acc.z; r.w = xv.w*acc.w;
    ((float4*)out)[t] = r;
}

extern "C" void kernel_launch(void* const* d_in, const int* in_sizes, int n_in,
                              void* d_out, int out_size, void* d_ws, size_t ws_size,
                              hipStream_t stream) {
    const float* x      = (const float*)d_in[0];
    const float* off_w1 = (const float*)d_in[1];
    const float* off_b1 = (const float*)d_in[2];
    const float* dw_w1  = (const float*)d_in[3];
    const float* off_w2 = (const float*)d_in[4];
    const float* off_b2 = (const float*)d_in[5];
    const float* dw_w2  = (const float*)d_in[6];
    const float* pw_w   = (const float*)d_in[7];
    const float* pw_b   = (const float*)d_in[8];
    float* out = (float*)d_out;

    const size_t nF    = (size_t)BB*CC*HW;
    const size_t attnB = nF*sizeof(float);
    const size_t off2B = (size_t)BB*98*HW*sizeof(float);   // fallback layout
    const size_t offTB = (size_t)BB*HW*112*sizeof(float);  // transposed offsets
    const size_t chB   = (size_t)BB*HW*64*sizeof(u16);
    char* ws = (char*)d_ws;

    const int n    = (int)nF;
    const int dbl  = n/64;
    const int pbl  = (n/4 + 255)/256;
    dim3 cblk(64,4);
    dim3 rgrd1(BB*(50/5), HH/4);
    dim3 rgrd2(BB*(98/7), HH/4);
    dim3 cgrd1(TGRID, 2);                    // conv1: 64 n / 32 per block
    dim3 cgrd2(TGRID, 4);                    // conv2: 128 n / 32 per block
    dim3 pgrd(TGRID, 4);                     // pw
    const int dgrid = BB*HW/8;               // 1568 (8 pixels per block)

    const size_t oOFF  = 0;
    const size_t oXT   = oOFF + offTB;
    const size_t oA1T  = oXT  + chB;
    const size_t oA2T  = oA1T + chB;
    const size_t oW1   = oA2T + chB;
    const size_t oW2   = oW1  + (size_t)R1*2;
    const size_t oPWT  = oW2  + (size_t)R2*2;
    const size_t oDW1  = oPWT + (size_t)R3*2;
    const size_t oDW2  = oDW1 + (size_t)R4*4;
    const size_t TOT   = oDW2 + (size_t)R5*4;   // ~11.47 MB

    if (ws_size >= TOT) {
        float* off_buf = (float*)(ws + oOFF);
        u16*   xT      = (u16*)(ws + oXT);
        u16*   a1T     = (u16*)(ws + oA1T);
        u16*   a2T     = (u16*)(ws + oA2T);
        u16*   w2t1    = (u16*)(ws + oW1);
        u16*   w2t2    = (u16*)(ws + oW2);
        u16*   pwT     = (u16*)(ws + oPWT);
        float* dwT1    = (float*)(ws + oDW1);
        float* dwT2    = (float*)(ws + oDW2);

        prep_tr_kernel<<<TGRID + (PREPN+255)/256, 256, 0, stream>>>(
            x, off_w1, off_w2, pw_w, dw_w1, dw_w2,
            xT, w2t1, w2t2, pwT, dwT1, dwT2);

        conv_mfma_lds_kernel<5,1,2,50,64,64,2><<<cgrd1, 256, 0, stream>>>(xT, w2t1, off_b1, off_buf);
        deform_cl_kernel<5,1,2,64><<<dgrid, 256, 0, stream>>>(xT, off_buf, dwT1, a1T);

        conv_mfma_lds_kernel<7,3,9,98,128,112,2><<<cgrd2, 256, 0, stream>>>(a1T, w2t2, off_b2, off_buf);
        deform_cl_kernel<7,3,9,112><<<dgrid, 256, 0, stream>>>(a1T, off_buf, dwT2, a2T);

        pw_mfma_kernel<<<pgrd, 256, 0, stream>>>(a2T, pwT, pw_b, x, out);
    } else if (ws_size >= off2B + attnB) {
        float* off_buf = (float*)ws;
        float* attn1   = (float*)d_out;
        float* attn2   = (float*)(ws + off2B);
        off_conv_sg_kernel<5,1,2,50,5><<<rgrd1, cblk, 0, stream>>>(x, off_w1, off_b1, off_buf);
        deform_dw_full_kernel<5,1,2><<<dbl, 64, 0, stream>>>(x, off_buf, dw_w1, attn1);
        off_conv_sg_kernel<7,3,9,98,7><<<rgrd2, cblk, 0, stream>>>(attn1, off_w2, off_b2, off_buf);
        deform_dw_full_kernel<7,3,9><<<dbl, 64, 0, stream>>>(attn1, off_buf, dw_w2, attn2);
        pw_mul_kernel<<<pbl, 256, 0, stream>>>(x, attn2, pw_w, pw_b, out);
    } else {
        float* attn1 = (float*)d_out;
        float* attn2 = (float*)ws;
        float* off1  = (float*)ws;
        off_conv_sg_kernel<5,1,2,50,5><<<rgrd1, cblk, 0, stream>>>(x, off_w1, off_b1, off1);
        deform_dw_full_kernel<5,1,2><<<dbl, 64, 0, stream>>>(x, off1, dw_w1, attn1);
        float* off2 = (float*)(ws + attnB);
        off_conv_sg_kernel<7,3,9,98,7><<<rgrd2, cblk, 0, stream>>>(attn1, off_w2, off_b2, off2);
        deform_dw_full_kernel<7,3,9><<<dbl, 64, 0, stream>>>(attn1, off2, dw_w2, attn2);
        pw_mul_kernel<<<pbl, 256, 0, stream>>>(x, attn2, pw_w, pw_b, out);
    }
}